// Round 5
// baseline (428.513 us; speedup 1.0000x reference)
//
#include <hip/hip_runtime.h>

typedef short bf16x8 __attribute__((ext_vector_type(8)));
typedef float f32x4 __attribute__((ext_vector_type(4)));

#define DI __device__ __forceinline__

#define LOG2E 1.44269504088896f
#define QSCALE (0.17677669529663687f * 1.44269504088896f)

static DI unsigned short f2bf(float f) {
  union { float f; unsigned u; } v; v.f = f;
  unsigned r = v.u + 0x7FFFu + ((v.u >> 16) & 1u);  // RNE
  return (unsigned short)(r >> 16);
}

static DI unsigned cvt_pk_bf16(float lo, float hi) {
  unsigned r;
  asm("v_cvt_pk_bf16_f32 %0, %1, %2" : "=v"(r) : "v"(lo), "v"(hi));
  return r;
}

static DI float bflo(unsigned u) { return __uint_as_float(u << 16); }
static DI float bfhi(unsigned u) { return __uint_as_float(u & 0xffff0000u); }

// ---------------------------------------------------------------------------
// Weight prep. Wt_qkvg: [N=1024][K=256] bf16 n-major. Wt_o: rows k-PERMUTED
// with pi(h*32+d) = h*32 + (d&15)*2 + (d>>4) to match attn_out's packed
// per-head column layout (k-permutation on both GEMM operands = no-op).
// ---------------------------------------------------------------------------
__global__ __launch_bounds__(256) void k_cast_weights(
    const float* __restrict__ Wq, const float* __restrict__ Wk,
    const float* __restrict__ Wv, const float* __restrict__ Wg,
    const float* __restrict__ Wo,
    unsigned short* __restrict__ Wt_qkvg, unsigned short* __restrict__ Wt_o) {
  int t = blockIdx.x * 256 + threadIdx.x;
  if (t < 262144) {
    int n = t & 1023, kk = t >> 10;
    const float* W = (n < 256) ? Wq : (n < 512) ? Wk : (n < 768) ? Wv : Wg;
    Wt_qkvg[(size_t)n * 256 + kk] = f2bf(W[kk * 256 + (n & 255)]);
  } else if (t < 262144 + 65536) {
    int u = t - 262144;
    int n = u & 255, kk = u >> 8;
    int h = kk >> 5, e = kk & 31;
    int d = (e >> 1) + ((e & 1) << 4);  // pi^-1
    Wt_o[n * 256 + kk] = f2bf(Wo[(h * 32 + d) * 256 + n]);
  }
}

// ---------------------------------------------------------------------------
// rmsnorm(m) -> bf16. One wave per 256-elem row, float4 per lane.
// ---------------------------------------------------------------------------
__global__ __launch_bounds__(256) void k_rmsnorm_m(
    const float* __restrict__ m, const float* __restrict__ w,
    unsigned short* __restrict__ m_norm) {
  int wave = threadIdx.x >> 6, lane = threadIdx.x & 63;
  int row = blockIdx.x * 4 + wave;
  const float4 x = *(const float4*)(m + (size_t)row * 256 + lane * 4);
  float ss = x.x * x.x + x.y * x.y + x.z * x.z + x.w * x.w;
#pragma unroll
  for (int mk = 1; mk < 64; mk <<= 1) ss += __shfl_xor(ss, mk, 64);
  float rms = rsqrtf(ss * (1.0f / 256.0f) + 1e-5f);
  const float4 wv = *(const float4*)(w + lane * 4);
  ushort4 o;
  o.x = f2bf(x.x * rms * wv.x);
  o.y = f2bf(x.y * rms * wv.y);
  o.z = f2bf(x.z * rms * wv.z);
  o.w = f2bf(x.w * rms * wv.w);
  *(ushort4*)(m_norm + (size_t)row * 256 + lane * 4) = o;
}

// ---------------------------------------------------------------------------
// Pair bias -> bf16 packed C-fragment layout, pre-scaled by log2(e):
// u32 biasf[h][i16][t][l][p] = pack(bias(i16*16+g*4+2p, t*16+c), bias(+1 row))
// with l = c + 16*g. Each wave: half 0 -> q-row i (even), half 1 -> i+1
// (same j-columns), so the row-pair pack is one shfl_xor(32) away.
// z loads stay fully coalesced (2x 512B per wave).
// ---------------------------------------------------------------------------
__global__ __launch_bounds__(256) void k_pair_bias(
    const float* __restrict__ z, const float* __restrict__ z_mask,
    const float* __restrict__ w_norm_z, const float* __restrict__ Wz,
    unsigned* __restrict__ biasf) {
  int gw = blockIdx.x * 4 + (threadIdx.x >> 6);   // global wave 0..16383
  int lane = threadIdx.x & 63;
  int half = lane >> 5, li = lane & 31;
  f32x4 wzl[4], wzh[4];
#pragma unroll
  for (int i = 0; i < 4; ++i) {
    wzl[i] = *(const f32x4*)(Wz + (li * 4 + i) * 8);
    wzh[i] = *(const f32x4*)(Wz + (li * 4 + i) * 8 + 4);
  }
  const float4 wn = *(const float4*)(w_norm_z + li * 4);

  for (int it = 0; it < 8; ++it) {
    int p = it * 16384 + gw;              // pair index 0..131071
    int i2 = p >> 9, j = p & 511;
    int irow = i2 * 2 + half;             // q-row
    int rr = irow * 512 + j;              // flat z row
    const float4 a = *(const float4*)(z + (size_t)rr * 128 + li * 4);
    float mb = (z_mask[rr] > 0.0f) ? 0.0f : -1e9f;

    float ss = a.x * a.x + a.y * a.y + a.z * a.z + a.w * a.w;
#pragma unroll
    for (int mk = 1; mk < 32; mk <<= 1) ss += __shfl_xor(ss, mk, 64);
    float rms = rsqrtf(ss * (1.0f / 128.0f) + 1e-5f);

    float y0 = a.x * wn.x, y1 = a.y * wn.y, y2 = a.z * wn.z, y3 = a.w * wn.w;
    f32x4 pl = y0 * wzl[0] + y1 * wzl[1] + y2 * wzl[2] + y3 * wzl[3];
    f32x4 ph = y0 * wzh[0] + y1 * wzh[1] + y2 * wzh[2] + y3 * wzh[3];

    int b0 = li & 1, b1 = (li >> 1) & 1, b2 = (li >> 2) & 1;
    float A[4] = {pl[0], pl[2], ph[0], ph[2]};
    float Bv[4] = {pl[1], pl[3], ph[1], ph[3]};
    float keep[4];
#pragma unroll
    for (int i = 0; i < 4; ++i) {
      float send = b0 ? A[i] : Bv[i];
      float recv = __shfl_xor(send, 1, 64);
      keep[i] = (b0 ? Bv[i] : A[i]) + recv;
    }
    float s2x = b1 ? keep[0] : keep[1];
    float s2y = b1 ? keep[2] : keep[3];
    float r2x = __shfl_xor(s2x, 2, 64);
    float r2y = __shfl_xor(s2y, 2, 64);
    float k2x = (b1 ? keep[1] : keep[0]) + r2x;
    float k2y = (b1 ? keep[3] : keep[2]) + r2y;
    float s3 = b2 ? k2x : k2y;
    float r3 = __shfl_xor(s3, 4, 64);
    float fin = (b2 ? k2y : k2x) + r3;           // head (li&7) partial (8 lanes)
    fin += __shfl_xor(fin, 8, 64);
    fin += __shfl_xor(fin, 16, 64);              // full 32-lane row sum

    float full = (fin * rms + mb) * LOG2E;
    float fo = __shfl_xor(full, 32, 64);         // partner half's row value
    if (half == 0 && li < 8) {
      unsigned pk = cvt_pk_bf16(full, fo);       // rows (i, i+1)
      int i = i2 * 2;
      int l = (j & 15) + 16 * ((i & 15) >> 2);
      size_t o = ((((size_t)li * 32 + (i >> 4)) * 32 + (j >> 4)) * 64 + l) * 2 +
                 ((i & 3) >> 1);
      biasf[o] = pk;
    }
  }
}

// ---------------------------------------------------------------------------
// Shared 128x128 MFMA GEMM mainloop (A row-major [M][256]).
// ---------------------------------------------------------------------------
DI void gemm_mainloop(const unsigned short* __restrict__ Amat,
                      const unsigned short* __restrict__ Btmat,
                      int mb, int nb, f32x4 acc[4][4],
                      unsigned short* At, unsigned short* Bts) {
  int tid = threadIdx.x, lane = tid & 63;
  int wm = (tid >> 6) >> 1, wn = (tid >> 6) & 1;
  int r16 = lane & 15, g8 = (lane >> 4) * 8;
  for (int kb = 0; kb < 256; kb += 32) {
#pragma unroll
    for (int u = 0; u < 2; ++u) {
      int c = u * 256 + tid;
      int rrow = c >> 2, gg = (c & 3) * 8;
      *(bf16x8*)(At + rrow * 40 + gg) =
          *(const bf16x8*)(Amat + (size_t)(mb + rrow) * 256 + kb + gg);
      *(bf16x8*)(Bts + rrow * 40 + gg) =
          *(const bf16x8*)(Btmat + (size_t)(nb + rrow) * 256 + kb + gg);
    }
    __syncthreads();
    bf16x8 af[4], bfr[4];
#pragma unroll
    for (int i = 0; i < 4; ++i)
      af[i] = *(const bf16x8*)(At + (wm * 64 + i * 16 + r16) * 40 + g8);
#pragma unroll
    for (int j = 0; j < 4; ++j)
      bfr[j] = *(const bf16x8*)(Bts + (wn * 64 + j * 16 + r16) * 40 + g8);
#pragma unroll
    for (int i = 0; i < 4; ++i)
#pragma unroll
      for (int j = 0; j < 4; ++j)
        acc[i][j] = __builtin_amdgcn_mfma_f32_16x16x32_bf16(af[i], bfr[j],
                                                            acc[i][j], 0, 0, 0);
    __syncthreads();
  }
}

// GEMM 1: m_norm @ [Wq|Wk|Wv|Wg]. q pre-scaled by 1/sqrt(D)*log2(e).
__global__ __launch_bounds__(256) void k_gemm_qkvg(
    const unsigned short* __restrict__ m_norm, const unsigned short* __restrict__ Wt,
    const float* __restrict__ bg,
    unsigned short* __restrict__ q_ws, unsigned short* __restrict__ k_ws,
    unsigned short* __restrict__ v_ws, float* __restrict__ g_ws) {
  __shared__ unsigned short At[128 * 40];
  __shared__ unsigned short Bts[128 * 40];
  int mb = blockIdx.x * 128, nb = blockIdx.y * 128;
  f32x4 acc[4][4] = {};
  gemm_mainloop(m_norm, Wt, mb, nb, acc, At, Bts);
  int lane = threadIdx.x & 63;
  int wm = (threadIdx.x >> 6) >> 1, wn = (threadIdx.x >> 6) & 1;
  int r16 = lane & 15, rg = lane >> 4;
#pragma unroll
  for (int i = 0; i < 4; ++i)
#pragma unroll
    for (int j = 0; j < 4; ++j) {
      int n = nb + wn * 64 + j * 16 + r16;
#pragma unroll
      for (int r = 0; r < 4; ++r) {
        int mrow = mb + wm * 64 + i * 16 + rg * 4 + r;
        int bb = mrow >> 9, s = mrow & 511;
        float v = acc[i][j][r];
        if (n < 768) {
          int tsel = n >> 8, hh = (n >> 5) & 7, dd = n & 31;
          unsigned short* dst = (tsel == 0) ? q_ws : (tsel == 1) ? k_ws : v_ws;
          float vv = (tsel == 0) ? v * QSCALE : v;
          dst[(((size_t)bb * 8 + hh) * 512 + s) * 32 + dd] = f2bf(vv);
        } else {
          int n2 = n & 255;
          g_ws[(size_t)mrow * 256 + n2] = v + bg[n2];
        }
      }
    }
}

// GEMM 2: attn_out [b][h][s][32] (pi-packed cols) @ Wt_o (rows pi-permuted),
// epilogue (+bo)*g -> fp32 out.
__global__ __launch_bounds__(256) void k_gemm_out(
    const unsigned short* __restrict__ attn, const unsigned short* __restrict__ Wt_o,
    const float* __restrict__ bo, const float* __restrict__ g_ws,
    float* __restrict__ out) {
  __shared__ unsigned short At[128 * 40];
  __shared__ unsigned short Bts[128 * 40];
  int mb = blockIdx.x * 128, nb = blockIdx.y * 128;
  int tid = threadIdx.x, lane = tid & 63;
  int wm = (tid >> 6) >> 1, wn = (tid >> 6) & 1;
  int r16 = lane & 15, g8 = (lane >> 4) * 8;
  f32x4 acc[4][4] = {};
  for (int kb = 0; kb < 256; kb += 32) {
    int hsel = kb >> 5;
#pragma unroll
    for (int u = 0; u < 2; ++u) {
      int c = u * 256 + tid;
      int rrow = c >> 2, gg = (c & 3) * 8;
      int mrow = mb + rrow;
      *(bf16x8*)(At + rrow * 40 + gg) =
          *(const bf16x8*)(attn +
              (((size_t)(mrow >> 9) * 8 + hsel) * 512 + (mrow & 511)) * 32 + gg);
      *(bf16x8*)(Bts + rrow * 40 + gg) =
          *(const bf16x8*)(Wt_o + (size_t)(nb + rrow) * 256 + kb + gg);
    }
    __syncthreads();
    bf16x8 af[4], bfr[4];
#pragma unroll
    for (int i = 0; i < 4; ++i)
      af[i] = *(const bf16x8*)(At + (wm * 64 + i * 16 + r16) * 40 + g8);
#pragma unroll
    for (int j = 0; j < 4; ++j)
      bfr[j] = *(const bf16x8*)(Bts + (wn * 64 + j * 16 + r16) * 40 + g8);
#pragma unroll
    for (int i = 0; i < 4; ++i)
#pragma unroll
      for (int j = 0; j < 4; ++j)
        acc[i][j] = __builtin_amdgcn_mfma_f32_16x16x32_bf16(af[i], bfr[j],
                                                            acc[i][j], 0, 0, 0);
    __syncthreads();
  }
  int rg = lane >> 4;
#pragma unroll
  for (int i = 0; i < 4; ++i)
#pragma unroll
    for (int j = 0; j < 4; ++j) {
      int n = nb + wn * 64 + j * 16 + r16;
#pragma unroll
      for (int r = 0; r < 4; ++r) {
        int mrow = mb + wm * 64 + i * 16 + rg * 4 + r;
        out[(size_t)mrow * 256 + n] = (acc[i][j][r] + bo[n]) * g_ws[(size_t)mrow * 256 + n];
      }
    }
}

// ---------------------------------------------------------------------------
// Attention. 1024 blocks: (h, b, S-half); 4 waves x 4 q-tiles of 16 rows.
// Full 16x512 score strip in regs; bias added post-MFMA from packed bf16
// fragment layout (1 dwordx2/lane/t, 512B/wave coalesced); no max pass
// (scores bounded << exp2 overflow; mask -1.4e9 -> exp2 = 0 exactly);
// unnormalized P -> PV; 1/sum at the packed-u32 per-head-contiguous output.
// ---------------------------------------------------------------------------
#define VT_LD 520
#define P_LD 40
__global__ __launch_bounds__(256, 3) void k_attn(
    const unsigned short* __restrict__ q_ws, const unsigned short* __restrict__ k_ws,
    const unsigned short* __restrict__ v_ws, const unsigned* __restrict__ biasf,
    unsigned short* __restrict__ attn_out) {
  __shared__ unsigned short Vt[32 * VT_LD];        // V^T slot-permuted (33,280 B)
  __shared__ unsigned short P_lds[4][16 * P_LD];   // per-wave P chunk (5,120 B)
  int tid = threadIdx.x;
  int wave = tid >> 6, lane = tid & 63;
  int bx = blockIdx.x;
  int h = bx >> 7, rb = bx & 127, b = rb >> 1, half = rb & 1;  // h-major: L2 share
  size_t base = ((size_t)b * 8 + h) * (512 * 32);
  const unsigned short* qb = q_ws + base;
  const unsigned short* kb = k_ws + base;
  const unsigned short* vb = v_ws + base;
  // stage V: read [s][d] coalesced; scatter to slot-permuted, XOR-swizzled Vt
#pragma unroll
  for (int it = 0; it < 8; ++it) {
    int idx = it * 256 + tid;
    int s = idx >> 2, kk = idx & 3, d0 = kk * 8;
    bf16x8 vv = *(const bf16x8*)(vb + s * 32 + d0);
    int slot = (s & ~31) | ((s & 15) << 1) | ((s >> 4) & 1);
    int sx = slot ^ (kk << 4);
#pragma unroll
    for (int j = 0; j < 8; ++j) Vt[(d0 + j) * VT_LD + sx] = (unsigned short)vv[j];
  }
  __syncthreads();

  int r16 = lane & 15, g = lane >> 4;
  const unsigned* bh_ = biasf + (size_t)h * 32 * 32 * 128 + lane * 2;
  unsigned short* Pl = &P_lds[wave][0];
  unsigned short* ob = attn_out + base;            // [b][h][s][32]

  for (int qt = 0; qt < 4; ++qt) {
    int qbase = half * 256 + (wave * 4 + qt) * 16;
    const unsigned* bq = bh_ + (size_t)(qbase >> 4) * 32 * 128;
    bf16x8 qf = *(const bf16x8*)(qb + (qbase + r16) * 32 + g * 8);
    const f32x4 zero = {0.f, 0.f, 0.f, 0.f};
    f32x4 sc[32];
#pragma unroll
    for (int t = 0; t < 32; ++t) {
      bf16x8 kf = *(const bf16x8*)(kb + (t * 16 + r16) * 32 + g * 8);
      sc[t] = __builtin_amdgcn_mfma_f32_16x16x32_bf16(qf, kf, zero, 0, 0, 0);
    }
    // + bias (packed bf16 fragment, coalesced dwordx2 per lane per t)
#pragma unroll
    for (int t = 0; t < 32; ++t) {
      uint2 u = *(const uint2*)(bq + t * 128);
      sc[t][0] += bflo(u.x);
      sc[t][1] += bfhi(u.x);
      sc[t][2] += bflo(u.y);
      sc[t][3] += bfhi(u.y);
    }
    // exp2 + row sum (no max: scores bounded, mask underflows to 0)
    float sm[4] = {0.f, 0.f, 0.f, 0.f};
#pragma unroll
    for (int t = 0; t < 32; ++t)
#pragma unroll
      for (int r = 0; r < 4; ++r) {
        float e = exp2f(sc[t][r]);
        sc[t][r] = e;
        sm[r] += e;
      }
#pragma unroll
    for (int r = 0; r < 4; ++r)
#pragma unroll
      for (int mk = 1; mk < 16; mk <<= 1) sm[r] += __shfl_xor(sm[r], mk, 64);
    float inv[4];
#pragma unroll
    for (int r = 0; r < 4; ++r) inv[r] = 1.0f / sm[r];

    // PV with unnormalized P; P packed 2 bf16 per u32 ds_write.
    f32x4 o0 = zero, o1 = zero;
    int rvx0 = (r16 >> 3) << 4;
    int rvx1 = ((r16 >> 3) + 2) << 4;
#pragma unroll
    for (int c = 0; c < 16; ++c) {
#pragma unroll
      for (int r = 0; r < 4; ++r) {
        unsigned pk = cvt_pk_bf16(sc[c * 2][r], sc[c * 2 + 1][r]);
        *(unsigned*)(Pl + (g * 4 + r) * P_LD + r16 * 2) = pk;
      }
      bf16x8 pf = *(const bf16x8*)(Pl + r16 * P_LD + g * 8);
      bf16x8 vf0 = *(const bf16x8*)(Vt + r16 * VT_LD + ((c * 32 + g * 8) ^ rvx0));
      bf16x8 vf1 = *(const bf16x8*)(Vt + (r16 + 16) * VT_LD + ((c * 32 + g * 8) ^ rvx1));
      o0 = __builtin_amdgcn_mfma_f32_16x16x32_bf16(pf, vf0, o0, 0, 0, 0);
      o1 = __builtin_amdgcn_mfma_f32_16x16x32_bf16(pf, vf1, o1, 0, 0, 0);
    }
#pragma unroll
    for (int r = 0; r < 4; ++r) {
      int s = qbase + g * 4 + r;
      unsigned pk = cvt_pk_bf16(o0[r] * inv[r], o1[r] * inv[r]);
      *(unsigned*)(ob + (size_t)s * 32 + r16 * 2) = pk;   // 64B runs, own lines
    }
  }
}

// ---------------------------------------------------------------------------
extern "C" void kernel_launch(void* const* d_in, const int* in_sizes, int n_in,
                              void* d_out, int out_size, void* d_ws, size_t ws_size,
                              hipStream_t stream) {
  (void)in_sizes; (void)n_in; (void)out_size; (void)ws_size;
  const float* m        = (const float*)d_in[0];
  const float* z        = (const float*)d_in[1];
  const float* z_mask   = (const float*)d_in[2];
  const float* w_norm_m = (const float*)d_in[3];
  const float* w_norm_z = (const float*)d_in[4];
  const float* Wq = (const float*)d_in[5];
  const float* Wk = (const float*)d_in[6];
  const float* Wv = (const float*)d_in[7];
  const float* Wz = (const float*)d_in[8];
  const float* Wg = (const float*)d_in[9];
  const float* bg = (const float*)d_in[10];
  const float* Wo = (const float*)d_in[11];
  const float* bo = (const float*)d_in[12];
  float* out = (float*)d_out;

  char* ws = (char*)d_ws;
  size_t off = 0;
  unsigned short* m_norm  = (unsigned short*)(ws + off); off += (size_t)32768 * 256 * 2;
  unsigned short* Wt_qkvg = (unsigned short*)(ws + off); off += (size_t)1024 * 256 * 2;
  unsigned short* Wt_o    = (unsigned short*)(ws + off); off += (size_t)256 * 256 * 2;
  unsigned short* q_ws    = (unsigned short*)(ws + off); off += (size_t)64 * 8 * 512 * 32 * 2;
  unsigned short* k_ws    = (unsigned short*)(ws + off); off += (size_t)64 * 8 * 512 * 32 * 2;
  unsigned short* v_ws    = (unsigned short*)(ws + off); off += (size_t)64 * 8 * 512 * 32 * 2;
  float* g_ws             = (float*)(ws + off);          off += (size_t)32768 * 256 * 4;
  unsigned* biasf         = (unsigned*)(ws + off);       off += (size_t)8 * 32 * 32 * 128 * 4;
  unsigned short* attn_out = m_norm;  // m_norm dead after k_gemm_qkvg

  hipLaunchKernelGGL(k_cast_weights, dim3(1280), dim3(256), 0, stream,
                     Wq, Wk, Wv, Wg, Wo, Wt_qkvg, Wt_o);
  hipLaunchKernelGGL(k_rmsnorm_m, dim3(8192), dim3(256), 0, stream, m, w_norm_m, m_norm);
  hipLaunchKernelGGL(k_pair_bias, dim3(4096), dim3(256), 0, stream,
                     z, z_mask, w_norm_z, Wz, biasf);
  hipLaunchKernelGGL(k_gemm_qkvg, dim3(256, 8), dim3(256), 0, stream,
                     m_norm, Wt_qkvg, bg, q_ws, k_ws, v_ws, g_ws);
  hipLaunchKernelGGL(k_attn, dim3(1024), dim3(256), 0, stream,
                     q_ws, k_ws, v_ws, biasf, attn_out);
  hipLaunchKernelGGL(k_gemm_out, dim3(256, 2), dim3(256), 0, stream,
                     attn_out, Wt_o, bo, g_ws, out);
}

// Round 6
// 224.268 us; speedup vs baseline: 1.9107x; 1.9107x over previous
//
#include <hip/hip_runtime.h>

typedef short bf16x8 __attribute__((ext_vector_type(8)));
typedef float f32x4 __attribute__((ext_vector_type(4)));

#define DI __device__ __forceinline__

#define LOG2E 1.44269504088896f
#define QSCALE (0.17677669529663687f * 1.44269504088896f)

static DI unsigned short f2bf(float f) {
  union { float f; unsigned u; } v; v.f = f;
  unsigned r = v.u + 0x7FFFu + ((v.u >> 16) & 1u);  // RNE
  return (unsigned short)(r >> 16);
}

static DI unsigned cvt_pk_bf16(float lo, float hi) {
  unsigned r;
  asm("v_cvt_pk_bf16_f32 %0, %1, %2" : "=v"(r) : "v"(lo), "v"(hi));
  return r;
}

static DI float bflo(unsigned u) { return __uint_as_float(u << 16); }
static DI float bfhi(unsigned u) { return __uint_as_float(u & 0xffff0000u); }

// ---------------------------------------------------------------------------
// Weight prep. Wt_qkvg: [N=1024][K=256] bf16 n-major. Wt_o: rows k-PERMUTED
// with pi(h*32+d) = h*32 + (d&15)*2 + (d>>4) to match attn_out's packed
// per-head column layout (k-permutation on both GEMM operands = no-op).
// ---------------------------------------------------------------------------
__global__ __launch_bounds__(256) void k_cast_weights(
    const float* __restrict__ Wq, const float* __restrict__ Wk,
    const float* __restrict__ Wv, const float* __restrict__ Wg,
    const float* __restrict__ Wo,
    unsigned short* __restrict__ Wt_qkvg, unsigned short* __restrict__ Wt_o) {
  int t = blockIdx.x * 256 + threadIdx.x;
  if (t < 262144) {
    int n = t & 1023, kk = t >> 10;
    const float* W = (n < 256) ? Wq : (n < 512) ? Wk : (n < 768) ? Wv : Wg;
    Wt_qkvg[(size_t)n * 256 + kk] = f2bf(W[kk * 256 + (n & 255)]);
  } else if (t < 262144 + 65536) {
    int u = t - 262144;
    int n = u & 255, kk = u >> 8;
    int h = kk >> 5, e = kk & 31;
    int d = (e >> 1) + ((e & 1) << 4);  // pi^-1
    Wt_o[n * 256 + kk] = f2bf(Wo[(h * 32 + d) * 256 + n]);
  }
}

// ---------------------------------------------------------------------------
// rmsnorm(m) -> bf16. One wave per 256-elem row, float4 per lane.
// ---------------------------------------------------------------------------
__global__ __launch_bounds__(256) void k_rmsnorm_m(
    const float* __restrict__ m, const float* __restrict__ w,
    unsigned short* __restrict__ m_norm) {
  int wave = threadIdx.x >> 6, lane = threadIdx.x & 63;
  int row = blockIdx.x * 4 + wave;
  const float4 x = *(const float4*)(m + (size_t)row * 256 + lane * 4);
  float ss = x.x * x.x + x.y * x.y + x.z * x.z + x.w * x.w;
#pragma unroll
  for (int mk = 1; mk < 64; mk <<= 1) ss += __shfl_xor(ss, mk, 64);
  float rms = rsqrtf(ss * (1.0f / 256.0f) + 1e-5f);
  const float4 wv = *(const float4*)(w + lane * 4);
  ushort4 o;
  o.x = f2bf(x.x * rms * wv.x);
  o.y = f2bf(x.y * rms * wv.y);
  o.z = f2bf(x.z * rms * wv.z);
  o.w = f2bf(x.w * rms * wv.w);
  *(ushort4*)(m_norm + (size_t)row * 256 + lane * 4) = o;
}

// ---------------------------------------------------------------------------
// Pair bias -> bf16 packed C-fragment layout, pre-scaled by log2(e):
// u32 biasf[h][i16][t][l][p] = pack(bias(i16*16+g*4+2p, t*16+c), bias(+1 row))
// with l = c + 16*g. Each wave: half 0 -> q-row i (even), half 1 -> i+1
// (same j-columns), so the row-pair pack is one shfl_xor(32) away.
// z loads stay fully coalesced (2x 512B per wave).
// ---------------------------------------------------------------------------
__global__ __launch_bounds__(256) void k_pair_bias(
    const float* __restrict__ z, const float* __restrict__ z_mask,
    const float* __restrict__ w_norm_z, const float* __restrict__ Wz,
    unsigned* __restrict__ biasf) {
  int gw = blockIdx.x * 4 + (threadIdx.x >> 6);   // global wave 0..16383
  int lane = threadIdx.x & 63;
  int half = lane >> 5, li = lane & 31;
  f32x4 wzl[4], wzh[4];
#pragma unroll
  for (int i = 0; i < 4; ++i) {
    wzl[i] = *(const f32x4*)(Wz + (li * 4 + i) * 8);
    wzh[i] = *(const f32x4*)(Wz + (li * 4 + i) * 8 + 4);
  }
  const float4 wn = *(const float4*)(w_norm_z + li * 4);

  for (int it = 0; it < 8; ++it) {
    int p = it * 16384 + gw;              // pair index 0..131071
    int i2 = p >> 9, j = p & 511;
    int irow = i2 * 2 + half;             // q-row
    int rr = irow * 512 + j;              // flat z row
    const float4 a = *(const float4*)(z + (size_t)rr * 128 + li * 4);
    float mb = (z_mask[rr] > 0.0f) ? 0.0f : -1e9f;

    float ss = a.x * a.x + a.y * a.y + a.z * a.z + a.w * a.w;
#pragma unroll
    for (int mk = 1; mk < 32; mk <<= 1) ss += __shfl_xor(ss, mk, 64);
    float rms = rsqrtf(ss * (1.0f / 128.0f) + 1e-5f);

    float y0 = a.x * wn.x, y1 = a.y * wn.y, y2 = a.z * wn.z, y3 = a.w * wn.w;
    f32x4 pl = y0 * wzl[0] + y1 * wzl[1] + y2 * wzl[2] + y3 * wzl[3];
    f32x4 ph = y0 * wzh[0] + y1 * wzh[1] + y2 * wzh[2] + y3 * wzh[3];

    int b0 = li & 1, b1 = (li >> 1) & 1, b2 = (li >> 2) & 1;
    float A[4] = {pl[0], pl[2], ph[0], ph[2]};
    float Bv[4] = {pl[1], pl[3], ph[1], ph[3]};
    float keep[4];
#pragma unroll
    for (int i = 0; i < 4; ++i) {
      float send = b0 ? A[i] : Bv[i];
      float recv = __shfl_xor(send, 1, 64);
      keep[i] = (b0 ? Bv[i] : A[i]) + recv;
    }
    float s2x = b1 ? keep[0] : keep[1];
    float s2y = b1 ? keep[2] : keep[3];
    float r2x = __shfl_xor(s2x, 2, 64);
    float r2y = __shfl_xor(s2y, 2, 64);
    float k2x = (b1 ? keep[1] : keep[0]) + r2x;
    float k2y = (b1 ? keep[3] : keep[2]) + r2y;
    float s3 = b2 ? k2x : k2y;
    float r3 = __shfl_xor(s3, 4, 64);
    float fin = (b2 ? k2y : k2x) + r3;           // head (li&7) partial (8 lanes)
    fin += __shfl_xor(fin, 8, 64);
    fin += __shfl_xor(fin, 16, 64);              // full 32-lane row sum

    float full = (fin * rms + mb) * LOG2E;
    float fo = __shfl_xor(full, 32, 64);         // partner half's row value
    if (half == 0 && li < 8) {
      unsigned pk = cvt_pk_bf16(full, fo);       // rows (i, i+1)
      int i = i2 * 2;
      int l = (j & 15) + 16 * ((i & 15) >> 2);
      size_t o = ((((size_t)li * 32 + (i >> 4)) * 32 + (j >> 4)) * 64 + l) * 2 +
                 ((i & 3) >> 1);
      biasf[o] = pk;
    }
  }
}

// ---------------------------------------------------------------------------
// Shared 128x128 MFMA GEMM mainloop (A row-major [M][256]).
// ---------------------------------------------------------------------------
DI void gemm_mainloop(const unsigned short* __restrict__ Amat,
                      const unsigned short* __restrict__ Btmat,
                      int mb, int nb, f32x4 acc[4][4],
                      unsigned short* At, unsigned short* Bts) {
  int tid = threadIdx.x, lane = tid & 63;
  int wm = (tid >> 6) >> 1, wn = (tid >> 6) & 1;
  int r16 = lane & 15, g8 = (lane >> 4) * 8;
  for (int kb = 0; kb < 256; kb += 32) {
#pragma unroll
    for (int u = 0; u < 2; ++u) {
      int c = u * 256 + tid;
      int rrow = c >> 2, gg = (c & 3) * 8;
      *(bf16x8*)(At + rrow * 40 + gg) =
          *(const bf16x8*)(Amat + (size_t)(mb + rrow) * 256 + kb + gg);
      *(bf16x8*)(Bts + rrow * 40 + gg) =
          *(const bf16x8*)(Btmat + (size_t)(nb + rrow) * 256 + kb + gg);
    }
    __syncthreads();
    bf16x8 af[4], bfr[4];
#pragma unroll
    for (int i = 0; i < 4; ++i)
      af[i] = *(const bf16x8*)(At + (wm * 64 + i * 16 + r16) * 40 + g8);
#pragma unroll
    for (int j = 0; j < 4; ++j)
      bfr[j] = *(const bf16x8*)(Bts + (wn * 64 + j * 16 + r16) * 40 + g8);
#pragma unroll
    for (int i = 0; i < 4; ++i)
#pragma unroll
      for (int j = 0; j < 4; ++j)
        acc[i][j] = __builtin_amdgcn_mfma_f32_16x16x32_bf16(af[i], bfr[j],
                                                            acc[i][j], 0, 0, 0);
    __syncthreads();
  }
}

// GEMM 1: m_norm @ [Wq|Wk|Wv|Wg]. q pre-scaled by 1/sqrt(D)*log2(e).
__global__ __launch_bounds__(256) void k_gemm_qkvg(
    const unsigned short* __restrict__ m_norm, const unsigned short* __restrict__ Wt,
    const float* __restrict__ bg,
    unsigned short* __restrict__ q_ws, unsigned short* __restrict__ k_ws,
    unsigned short* __restrict__ v_ws, float* __restrict__ g_ws) {
  __shared__ unsigned short At[128 * 40];
  __shared__ unsigned short Bts[128 * 40];
  int mb = blockIdx.x * 128, nb = blockIdx.y * 128;
  f32x4 acc[4][4] = {};
  gemm_mainloop(m_norm, Wt, mb, nb, acc, At, Bts);
  int lane = threadIdx.x & 63;
  int wm = (threadIdx.x >> 6) >> 1, wn = (threadIdx.x >> 6) & 1;
  int r16 = lane & 15, rg = lane >> 4;
#pragma unroll
  for (int i = 0; i < 4; ++i)
#pragma unroll
    for (int j = 0; j < 4; ++j) {
      int n = nb + wn * 64 + j * 16 + r16;
#pragma unroll
      for (int r = 0; r < 4; ++r) {
        int mrow = mb + wm * 64 + i * 16 + rg * 4 + r;
        int bb = mrow >> 9, s = mrow & 511;
        float v = acc[i][j][r];
        if (n < 768) {
          int tsel = n >> 8, hh = (n >> 5) & 7, dd = n & 31;
          unsigned short* dst = (tsel == 0) ? q_ws : (tsel == 1) ? k_ws : v_ws;
          float vv = (tsel == 0) ? v * QSCALE : v;
          dst[(((size_t)bb * 8 + hh) * 512 + s) * 32 + dd] = f2bf(vv);
        } else {
          int n2 = n & 255;
          g_ws[(size_t)mrow * 256 + n2] = v + bg[n2];
        }
      }
    }
}

// GEMM 2: attn_out [b][h][s][32] (pi-packed cols) @ Wt_o (rows pi-permuted),
// epilogue (+bo)*g -> fp32 out.
__global__ __launch_bounds__(256) void k_gemm_out(
    const unsigned short* __restrict__ attn, const unsigned short* __restrict__ Wt_o,
    const float* __restrict__ bo, const float* __restrict__ g_ws,
    float* __restrict__ out) {
  __shared__ unsigned short At[128 * 40];
  __shared__ unsigned short Bts[128 * 40];
  int mb = blockIdx.x * 128, nb = blockIdx.y * 128;
  int tid = threadIdx.x, lane = tid & 63;
  int wm = (tid >> 6) >> 1, wn = (tid >> 6) & 1;
  int r16 = lane & 15, g8 = (lane >> 4) * 8;
  f32x4 acc[4][4] = {};
  for (int kb = 0; kb < 256; kb += 32) {
    int hsel = kb >> 5;
#pragma unroll
    for (int u = 0; u < 2; ++u) {
      int c = u * 256 + tid;
      int rrow = c >> 2, gg = (c & 3) * 8;
      int mrow = mb + rrow;
      *(bf16x8*)(At + rrow * 40 + gg) =
          *(const bf16x8*)(attn +
              (((size_t)(mrow >> 9) * 8 + hsel) * 512 + (mrow & 511)) * 32 + gg);
      *(bf16x8*)(Bts + rrow * 40 + gg) =
          *(const bf16x8*)(Wt_o + (size_t)(nb + rrow) * 256 + kb + gg);
    }
    __syncthreads();
    bf16x8 af[4], bfr[4];
#pragma unroll
    for (int i = 0; i < 4; ++i)
      af[i] = *(const bf16x8*)(At + (wm * 64 + i * 16 + r16) * 40 + g8);
#pragma unroll
    for (int j = 0; j < 4; ++j)
      bfr[j] = *(const bf16x8*)(Bts + (wn * 64 + j * 16 + r16) * 40 + g8);
#pragma unroll
    for (int i = 0; i < 4; ++i)
#pragma unroll
      for (int j = 0; j < 4; ++j)
        acc[i][j] = __builtin_amdgcn_mfma_f32_16x16x32_bf16(af[i], bfr[j],
                                                            acc[i][j], 0, 0, 0);
    __syncthreads();
  }
  int rg = lane >> 4;
#pragma unroll
  for (int i = 0; i < 4; ++i)
#pragma unroll
    for (int j = 0; j < 4; ++j) {
      int n = nb + wn * 64 + j * 16 + r16;
#pragma unroll
      for (int r = 0; r < 4; ++r) {
        int mrow = mb + wm * 64 + i * 16 + rg * 4 + r;
        out[(size_t)mrow * 256 + n] = (acc[i][j][r] + bo[n]) * g_ws[(size_t)mrow * 256 + n];
      }
    }
}

// ---------------------------------------------------------------------------
// Attention, R6: FUSED chunk loop. No score strip — per 32-col chunk:
// 2x QK MFMA -> +bias (packed bf16 frag, dwordx2) -> exp2 -> pack P (u32
// ds_write) -> 2x PV MFMA. Live state ~70 VGPR (vs 128+ strip): no spills,
// 4 blocks/CU (LDS 38.4KB), 16 waves/CU for latency hiding. No max pass
// (scores bounded; mask -1.4e9 -> exp2 = 0). 1/sum applied at output.
// 1024 blocks: (h, b, S-half), h-major for K/V/bias L2 sharing.
// ---------------------------------------------------------------------------
#define VT_LD 520
#define P_LD 40
__global__ __launch_bounds__(256, 2) void k_attn(
    const unsigned short* __restrict__ q_ws, const unsigned short* __restrict__ k_ws,
    const unsigned short* __restrict__ v_ws, const unsigned* __restrict__ biasf,
    unsigned short* __restrict__ attn_out) {
  __shared__ unsigned short Vt[32 * VT_LD];        // V^T slot-permuted (33,280 B)
  __shared__ unsigned short P_lds[4][16 * P_LD];   // per-wave P chunk (5,120 B)
  int tid = threadIdx.x;
  int wave = tid >> 6, lane = tid & 63;
  int bx = blockIdx.x;
  int h = bx >> 7, rb = bx & 127, b = rb >> 1, half = rb & 1;  // h-major
  size_t base = ((size_t)b * 8 + h) * (512 * 32);
  const unsigned short* qb = q_ws + base;
  const unsigned short* kb = k_ws + base;
  const unsigned short* vb = v_ws + base;
  // stage V: read [s][d] coalesced; scatter to slot-permuted, XOR-swizzled Vt
#pragma unroll
  for (int it = 0; it < 8; ++it) {
    int idx = it * 256 + tid;
    int s = idx >> 2, kk = idx & 3, d0 = kk * 8;
    bf16x8 vv = *(const bf16x8*)(vb + s * 32 + d0);
    int slot = (s & ~31) | ((s & 15) << 1) | ((s >> 4) & 1);
    int sx = slot ^ (kk << 4);
#pragma unroll
    for (int j = 0; j < 8; ++j) Vt[(d0 + j) * VT_LD + sx] = (unsigned short)vv[j];
  }
  __syncthreads();

  int r16 = lane & 15, g = lane >> 4;
  const unsigned* bh_ = biasf + (size_t)h * 131072 + lane * 2;
  unsigned short* Pl = &P_lds[wave][0];
  unsigned short* ob = attn_out + base;            // [b][h][s][32]
  int rvx0 = (r16 >> 3) << 4;
  int rvx1 = ((r16 >> 3) + 2) << 4;
  const f32x4 zero = {0.f, 0.f, 0.f, 0.f};

  for (int qt = 0; qt < 4; ++qt) {
    int qbase = half * 256 + (wave * 4 + qt) * 16;
    const unsigned* bq = bh_ + (size_t)(qbase >> 4) * 4096;
    bf16x8 qf = *(const bf16x8*)(qb + (qbase + r16) * 32 + g * 8);
    f32x4 o0 = zero, o1 = zero;
    f32x4 sm = zero;
#pragma unroll
    for (int c = 0; c < 16; ++c) {
      bf16x8 kf0 = *(const bf16x8*)(kb + ((c * 2) * 16 + r16) * 32 + g * 8);
      bf16x8 kf1 = *(const bf16x8*)(kb + ((c * 2 + 1) * 16 + r16) * 32 + g * 8);
      uint2 u0 = *(const uint2*)(bq + (c * 2) * 128);
      uint2 u1 = *(const uint2*)(bq + (c * 2 + 1) * 128);
      f32x4 s0 = __builtin_amdgcn_mfma_f32_16x16x32_bf16(qf, kf0, zero, 0, 0, 0);
      f32x4 s1 = __builtin_amdgcn_mfma_f32_16x16x32_bf16(qf, kf1, zero, 0, 0, 0);
      s0[0] += bflo(u0.x); s0[1] += bfhi(u0.x);
      s0[2] += bflo(u0.y); s0[3] += bfhi(u0.y);
      s1[0] += bflo(u1.x); s1[1] += bfhi(u1.x);
      s1[2] += bflo(u1.y); s1[3] += bfhi(u1.y);
#pragma unroll
      for (int r = 0; r < 4; ++r) {
        s0[r] = exp2f(s0[r]);
        s1[r] = exp2f(s1[r]);
        sm[r] += s0[r] + s1[r];
      }
#pragma unroll
      for (int r = 0; r < 4; ++r) {
        unsigned pk = cvt_pk_bf16(s0[r], s1[r]);
        *(unsigned*)(Pl + (g * 4 + r) * P_LD + r16 * 2) = pk;
      }
      bf16x8 pf = *(const bf16x8*)(Pl + r16 * P_LD + g * 8);
      bf16x8 vf0 = *(const bf16x8*)(Vt + r16 * VT_LD + ((c * 32 + g * 8) ^ rvx0));
      bf16x8 vf1 = *(const bf16x8*)(Vt + (r16 + 16) * VT_LD + ((c * 32 + g * 8) ^ rvx1));
      o0 = __builtin_amdgcn_mfma_f32_16x16x32_bf16(pf, vf0, o0, 0, 0, 0);
      o1 = __builtin_amdgcn_mfma_f32_16x16x32_bf16(pf, vf1, o1, 0, 0, 0);
    }
#pragma unroll
    for (int r = 0; r < 4; ++r)
#pragma unroll
      for (int mk = 1; mk < 16; mk <<= 1) sm[r] += __shfl_xor(sm[r], mk, 64);
#pragma unroll
    for (int r = 0; r < 4; ++r) {
      int s = qbase + g * 4 + r;
      float inv = 1.0f / sm[r];
      unsigned pk = cvt_pk_bf16(o0[r] * inv, o1[r] * inv);
      *(unsigned*)(ob + (size_t)s * 32 + r16 * 2) = pk;   // 64B runs, own lines
    }
  }
}

// ---------------------------------------------------------------------------
extern "C" void kernel_launch(void* const* d_in, const int* in_sizes, int n_in,
                              void* d_out, int out_size, void* d_ws, size_t ws_size,
                              hipStream_t stream) {
  (void)in_sizes; (void)n_in; (void)out_size; (void)ws_size;
  const float* m        = (const float*)d_in[0];
  const float* z        = (const float*)d_in[1];
  const float* z_mask   = (const float*)d_in[2];
  const float* w_norm_m = (const float*)d_in[3];
  const float* w_norm_z = (const float*)d_in[4];
  const float* Wq = (const float*)d_in[5];
  const float* Wk = (const float*)d_in[6];
  const float* Wv = (const float*)d_in[7];
  const float* Wz = (const float*)d_in[8];
  const float* Wg = (const float*)d_in[9];
  const float* bg = (const float*)d_in[10];
  const float* Wo = (const float*)d_in[11];
  const float* bo = (const float*)d_in[12];
  float* out = (float*)d_out;

  char* ws = (char*)d_ws;
  size_t off = 0;
  unsigned short* m_norm  = (unsigned short*)(ws + off); off += (size_t)32768 * 256 * 2;
  unsigned short* Wt_qkvg = (unsigned short*)(ws + off); off += (size_t)1024 * 256 * 2;
  unsigned short* Wt_o    = (unsigned short*)(ws + off); off += (size_t)256 * 256 * 2;
  unsigned short* q_ws    = (unsigned short*)(ws + off); off += (size_t)64 * 8 * 512 * 32 * 2;
  unsigned short* k_ws    = (unsigned short*)(ws + off); off += (size_t)64 * 8 * 512 * 32 * 2;
  unsigned short* v_ws    = (unsigned short*)(ws + off); off += (size_t)64 * 8 * 512 * 32 * 2;
  float* g_ws             = (float*)(ws + off);          off += (size_t)32768 * 256 * 4;
  unsigned* biasf         = (unsigned*)(ws + off);       off += (size_t)8 * 32 * 32 * 128 * 4;
  unsigned short* attn_out = m_norm;  // m_norm dead after k_gemm_qkvg

  hipLaunchKernelGGL(k_cast_weights, dim3(1280), dim3(256), 0, stream,
                     Wq, Wk, Wv, Wg, Wo, Wt_qkvg, Wt_o);
  hipLaunchKernelGGL(k_rmsnorm_m, dim3(8192), dim3(256), 0, stream, m, w_norm_m, m_norm);
  hipLaunchKernelGGL(k_pair_bias, dim3(4096), dim3(256), 0, stream,
                     z, z_mask, w_norm_z, Wz, biasf);
  hipLaunchKernelGGL(k_gemm_qkvg, dim3(256, 8), dim3(256), 0, stream,
                     m_norm, Wt_qkvg, bg, q_ws, k_ws, v_ws, g_ws);
  hipLaunchKernelGGL(k_attn, dim3(1024), dim3(256), 0, stream,
                     q_ws, k_ws, v_ws, biasf, attn_out);
  hipLaunchKernelGGL(k_gemm_out, dim3(256, 2), dim3(256), 0, stream,
                     attn_out, Wt_o, bo, g_ws, out);
}

// Round 7
// 192.080 us; speedup vs baseline: 2.2309x; 1.1676x over previous
//
#include <hip/hip_runtime.h>

typedef short bf16x8 __attribute__((ext_vector_type(8)));
typedef float f32x4 __attribute__((ext_vector_type(4)));

#define DI __device__ __forceinline__

#define LOG2E 1.44269504088896f
#define QSCALE (0.17677669529663687f * 1.44269504088896f)

static DI unsigned short f2bf(float f) {
  union { float f; unsigned u; } v; v.f = f;
  unsigned r = v.u + 0x7FFFu + ((v.u >> 16) & 1u);  // RNE
  return (unsigned short)(r >> 16);
}

static DI unsigned cvt_pk_bf16(float lo, float hi) {
  unsigned r;
  asm("v_cvt_pk_bf16_f32 %0, %1, %2" : "=v"(r) : "v"(lo), "v"(hi));
  return r;
}

static DI float bflo(unsigned u) { return __uint_as_float(u << 16); }
static DI float bfhi(unsigned u) { return __uint_as_float(u & 0xffff0000u); }

// ---------------------------------------------------------------------------
// Weight prep. Wt_qkvg: [N=1024][K=256] bf16 n-major. Wt_o: rows k-PERMUTED
// with pi(h*32+d) = h*32 + (d&15)*2 + (d>>4) to match attn_out's packed
// per-head column layout (k-permutation on both GEMM operands = no-op).
// ---------------------------------------------------------------------------
__global__ __launch_bounds__(256) void k_cast_weights(
    const float* __restrict__ Wq, const float* __restrict__ Wk,
    const float* __restrict__ Wv, const float* __restrict__ Wg,
    const float* __restrict__ Wo,
    unsigned short* __restrict__ Wt_qkvg, unsigned short* __restrict__ Wt_o) {
  int t = blockIdx.x * 256 + threadIdx.x;
  if (t < 262144) {
    int n = t & 1023, kk = t >> 10;
    const float* W = (n < 256) ? Wq : (n < 512) ? Wk : (n < 768) ? Wv : Wg;
    Wt_qkvg[(size_t)n * 256 + kk] = f2bf(W[kk * 256 + (n & 255)]);
  } else if (t < 262144 + 65536) {
    int u = t - 262144;
    int n = u & 255, kk = u >> 8;
    int h = kk >> 5, e = kk & 31;
    int d = (e >> 1) + ((e & 1) << 4);  // pi^-1
    Wt_o[n * 256 + kk] = f2bf(Wo[(h * 32 + d) * 256 + n]);
  }
}

// ---------------------------------------------------------------------------
// rmsnorm(m) -> bf16. One wave per 256-elem row, float4 per lane.
// ---------------------------------------------------------------------------
__global__ __launch_bounds__(256) void k_rmsnorm_m(
    const float* __restrict__ m, const float* __restrict__ w,
    unsigned short* __restrict__ m_norm) {
  int wave = threadIdx.x >> 6, lane = threadIdx.x & 63;
  int row = blockIdx.x * 4 + wave;
  const float4 x = *(const float4*)(m + (size_t)row * 256 + lane * 4);
  float ss = x.x * x.x + x.y * x.y + x.z * x.z + x.w * x.w;
#pragma unroll
  for (int mk = 1; mk < 64; mk <<= 1) ss += __shfl_xor(ss, mk, 64);
  float rms = rsqrtf(ss * (1.0f / 256.0f) + 1e-5f);
  const float4 wv = *(const float4*)(w + lane * 4);
  ushort4 o;
  o.x = f2bf(x.x * rms * wv.x);
  o.y = f2bf(x.y * rms * wv.y);
  o.z = f2bf(x.z * rms * wv.z);
  o.w = f2bf(x.w * rms * wv.w);
  *(ushort4*)(m_norm + (size_t)row * 256 + lane * 4) = o;
}

// ---------------------------------------------------------------------------
// Pair bias -> bf16 packed SWAPPED-C-fragment layout, pre-scaled by log2(e).
// Attn computes D[k][q] = mfma(K,Q): lane l needs bias(i=q=l&15 of its tile,
// k = t*16 + 4*(l>>4) + r). Pack pairs along k (j0 even, j0+1):
//   u32 biasf[h][i16][t][l][w], l = (i&15) + 16*((j0&15)>>2), w = (j0>>1)&1
// Wave: half 0 -> j0 (even), half 1 -> j0+1, same i; pack via shfl_xor(32).
// z loads coalesced (2 adjacent rows = 1KB per wave).
// ---------------------------------------------------------------------------
__global__ __launch_bounds__(256) void k_pair_bias(
    const float* __restrict__ z, const float* __restrict__ z_mask,
    const float* __restrict__ w_norm_z, const float* __restrict__ Wz,
    unsigned* __restrict__ biasf) {
  int gw = blockIdx.x * 4 + (threadIdx.x >> 6);   // global wave 0..16383
  int lane = threadIdx.x & 63;
  int half = lane >> 5, li = lane & 31;
  f32x4 wzl[4], wzh[4];
#pragma unroll
  for (int i = 0; i < 4; ++i) {
    wzl[i] = *(const f32x4*)(Wz + (li * 4 + i) * 8);
    wzh[i] = *(const f32x4*)(Wz + (li * 4 + i) * 8 + 4);
  }
  const float4 wn = *(const float4*)(w_norm_z + li * 4);

  for (int it = 0; it < 8; ++it) {
    int p = it * 16384 + gw;              // pair index 0..131071
    int i = p >> 8, jp = p & 255;
    int j = jp * 2 + half;                // k-col
    int rr = i * 512 + j;                 // flat z row
    const float4 a = *(const float4*)(z + (size_t)rr * 128 + li * 4);
    float mb = (z_mask[rr] > 0.0f) ? 0.0f : -1e9f;

    float ss = a.x * a.x + a.y * a.y + a.z * a.z + a.w * a.w;
#pragma unroll
    for (int mk = 1; mk < 32; mk <<= 1) ss += __shfl_xor(ss, mk, 64);
    float rms = rsqrtf(ss * (1.0f / 128.0f) + 1e-5f);

    float y0 = a.x * wn.x, y1 = a.y * wn.y, y2 = a.z * wn.z, y3 = a.w * wn.w;
    f32x4 pl = y0 * wzl[0] + y1 * wzl[1] + y2 * wzl[2] + y3 * wzl[3];
    f32x4 ph = y0 * wzh[0] + y1 * wzh[1] + y2 * wzh[2] + y3 * wzh[3];

    int b0 = li & 1, b1 = (li >> 1) & 1, b2 = (li >> 2) & 1;
    float A[4] = {pl[0], pl[2], ph[0], ph[2]};
    float Bv[4] = {pl[1], pl[3], ph[1], ph[3]};
    float keep[4];
#pragma unroll
    for (int i2 = 0; i2 < 4; ++i2) {
      float send = b0 ? A[i2] : Bv[i2];
      float recv = __shfl_xor(send, 1, 64);
      keep[i2] = (b0 ? Bv[i2] : A[i2]) + recv;
    }
    float s2x = b1 ? keep[0] : keep[1];
    float s2y = b1 ? keep[2] : keep[3];
    float r2x = __shfl_xor(s2x, 2, 64);
    float r2y = __shfl_xor(s2y, 2, 64);
    float k2x = (b1 ? keep[1] : keep[0]) + r2x;
    float k2y = (b1 ? keep[3] : keep[2]) + r2y;
    float s3 = b2 ? k2x : k2y;
    float r3 = __shfl_xor(s3, 4, 64);
    float fin = (b2 ? k2y : k2x) + r3;           // head (li&7) partial (8 lanes)
    fin += __shfl_xor(fin, 8, 64);
    fin += __shfl_xor(fin, 16, 64);              // full 32-lane row sum

    float full = (fin * rms + mb) * LOG2E;
    float fo = __shfl_xor(full, 32, 64);         // partner (j0+1) value
    if (half == 0 && li < 8) {
      unsigned pk = cvt_pk_bf16(full, fo);       // (j0, j0+1)
      int j0 = jp * 2;
      int l = (i & 15) + 16 * ((j0 & 15) >> 2);
      size_t o = ((((size_t)li * 32 + (i >> 4)) * 32 + (j0 >> 4)) * 64 + l) * 2 +
                 ((jp) & 1);
      biasf[o] = pk;
    }
  }
}

// ---------------------------------------------------------------------------
// Shared 128x128 MFMA GEMM mainloop (A row-major [M][256]).
// ---------------------------------------------------------------------------
DI void gemm_mainloop(const unsigned short* __restrict__ Amat,
                      const unsigned short* __restrict__ Btmat,
                      int mb, int nb, f32x4 acc[4][4],
                      unsigned short* At, unsigned short* Bts) {
  int tid = threadIdx.x, lane = tid & 63;
  int wm = (tid >> 6) >> 1, wn = (tid >> 6) & 1;
  int r16 = lane & 15, g8 = (lane >> 4) * 8;
  for (int kb = 0; kb < 256; kb += 32) {
#pragma unroll
    for (int u = 0; u < 2; ++u) {
      int c = u * 256 + tid;
      int rrow = c >> 2, gg = (c & 3) * 8;
      *(bf16x8*)(At + rrow * 40 + gg) =
          *(const bf16x8*)(Amat + (size_t)(mb + rrow) * 256 + kb + gg);
      *(bf16x8*)(Bts + rrow * 40 + gg) =
          *(const bf16x8*)(Btmat + (size_t)(nb + rrow) * 256 + kb + gg);
    }
    __syncthreads();
    bf16x8 af[4], bfr[4];
#pragma unroll
    for (int i = 0; i < 4; ++i)
      af[i] = *(const bf16x8*)(At + (wm * 64 + i * 16 + r16) * 40 + g8);
#pragma unroll
    for (int j = 0; j < 4; ++j)
      bfr[j] = *(const bf16x8*)(Bts + (wn * 64 + j * 16 + r16) * 40 + g8);
#pragma unroll
    for (int i = 0; i < 4; ++i)
#pragma unroll
      for (int j = 0; j < 4; ++j)
        acc[i][j] = __builtin_amdgcn_mfma_f32_16x16x32_bf16(af[i], bfr[j],
                                                            acc[i][j], 0, 0, 0);
    __syncthreads();
  }
}

// GEMM 1: m_norm @ [Wq|Wk|Wv|Wg]. q pre-scaled by 1/sqrt(D)*log2(e).
__global__ __launch_bounds__(256) void k_gemm_qkvg(
    const unsigned short* __restrict__ m_norm, const unsigned short* __restrict__ Wt,
    const float* __restrict__ bg,
    unsigned short* __restrict__ q_ws, unsigned short* __restrict__ k_ws,
    unsigned short* __restrict__ v_ws, float* __restrict__ g_ws) {
  __shared__ unsigned short At[128 * 40];
  __shared__ unsigned short Bts[128 * 40];
  int mb = blockIdx.x * 128, nb = blockIdx.y * 128;
  f32x4 acc[4][4] = {};
  gemm_mainloop(m_norm, Wt, mb, nb, acc, At, Bts);
  int lane = threadIdx.x & 63;
  int wm = (threadIdx.x >> 6) >> 1, wn = (threadIdx.x >> 6) & 1;
  int r16 = lane & 15, rg = lane >> 4;
#pragma unroll
  for (int i = 0; i < 4; ++i)
#pragma unroll
    for (int j = 0; j < 4; ++j) {
      int n = nb + wn * 64 + j * 16 + r16;
#pragma unroll
      for (int r = 0; r < 4; ++r) {
        int mrow = mb + wm * 64 + i * 16 + rg * 4 + r;
        int bb = mrow >> 9, s = mrow & 511;
        float v = acc[i][j][r];
        if (n < 768) {
          int tsel = n >> 8, hh = (n >> 5) & 7, dd = n & 31;
          unsigned short* dst = (tsel == 0) ? q_ws : (tsel == 1) ? k_ws : v_ws;
          float vv = (tsel == 0) ? v * QSCALE : v;
          dst[(((size_t)bb * 8 + hh) * 512 + s) * 32 + dd] = f2bf(vv);
        } else {
          int n2 = n & 255;
          g_ws[(size_t)mrow * 256 + n2] = v + bg[n2];
        }
      }
    }
}

// GEMM 2: attn_out [b][h][s][32] (pi-packed cols) @ Wt_o (rows pi-permuted),
// epilogue (+bo)*g -> fp32 out.
__global__ __launch_bounds__(256) void k_gemm_out(
    const unsigned short* __restrict__ attn, const unsigned short* __restrict__ Wt_o,
    const float* __restrict__ bo, const float* __restrict__ g_ws,
    float* __restrict__ out) {
  __shared__ unsigned short At[128 * 40];
  __shared__ unsigned short Bts[128 * 40];
  int mb = blockIdx.x * 128, nb = blockIdx.y * 128;
  int tid = threadIdx.x, lane = tid & 63;
  int wm = (tid >> 6) >> 1, wn = (tid >> 6) & 1;
  int r16 = lane & 15, g8 = (lane >> 4) * 8;
  f32x4 acc[4][4] = {};
  for (int kb = 0; kb < 256; kb += 32) {
    int hsel = kb >> 5;
#pragma unroll
    for (int u = 0; u < 2; ++u) {
      int c = u * 256 + tid;
      int rrow = c >> 2, gg = (c & 3) * 8;
      int mrow = mb + rrow;
      *(bf16x8*)(At + rrow * 40 + gg) =
          *(const bf16x8*)(attn +
              (((size_t)(mrow >> 9) * 8 + hsel) * 512 + (mrow & 511)) * 32 + gg);
      *(bf16x8*)(Bts + rrow * 40 + gg) =
          *(const bf16x8*)(Wt_o + (size_t)(nb + rrow) * 256 + kb + gg);
    }
    __syncthreads();
    bf16x8 af[4], bfr[4];
#pragma unroll
    for (int i = 0; i < 4; ++i)
      af[i] = *(const bf16x8*)(At + (wm * 64 + i * 16 + r16) * 40 + g8);
#pragma unroll
    for (int j = 0; j < 4; ++j)
      bfr[j] = *(const bf16x8*)(Bts + (wn * 64 + j * 16 + r16) * 40 + g8);
#pragma unroll
    for (int i = 0; i < 4; ++i)
#pragma unroll
      for (int j = 0; j < 4; ++j)
        acc[i][j] = __builtin_amdgcn_mfma_f32_16x16x32_bf16(af[i], bfr[j],
                                                            acc[i][j], 0, 0, 0);
    __syncthreads();
  }
  int rg = lane >> 4;
#pragma unroll
  for (int i = 0; i < 4; ++i)
#pragma unroll
    for (int j = 0; j < 4; ++j) {
      int n = nb + wn * 64 + j * 16 + r16;
#pragma unroll
      for (int r = 0; r < 4; ++r) {
        int mrow = mb + wm * 64 + i * 16 + rg * 4 + r;
        out[(size_t)mrow * 256 + n] = (acc[i][j][r] + bo[n]) * g_ws[(size_t)mrow * 256 + n];
      }
    }
}

// ---------------------------------------------------------------------------
// Attention, R7: swapped QK^T (mfma(K,Q) -> D[k][q], q = lane&15) so P is a
// valid PV A-operand IN REGISTERS (4 cvt_pk, no LDS round trip). PV k-order
// sigma: group g holds k in {4g..4g+3, 16+4g..16+4g+3}; V staged at slot
// 8*((sc>>2)&3) + 4*((sc>>4)&1) + (sc&3) so vf = one ds_read_b128. VT_LD=522
// (odd dword stride) spreads staging-scatter banks. Row sums = per-lane
// scalars (no shuffles in loop); normalization inv via 2 shfl + 4 bpermute.
// Grid 2048 = quarter*512 + h*64 + b (quarters of (b,h) on same XCD).
// ---------------------------------------------------------------------------
#define VT_LD 522
__global__ __launch_bounds__(256, 2) void k_attn(
    const unsigned short* __restrict__ q_ws, const unsigned short* __restrict__ k_ws,
    const unsigned short* __restrict__ v_ws, const unsigned* __restrict__ biasf,
    unsigned short* __restrict__ attn_out) {
  __shared__ unsigned short Vt[32 * VT_LD];        // 33,408 B
  int tid = threadIdx.x;
  int wave = tid >> 6, lane = tid & 63;
  int bx = blockIdx.x;
  int quarter = bx >> 9, h = (bx >> 6) & 7, b = bx & 63;
  size_t base = ((size_t)b * 8 + h) * (512 * 32);
  const unsigned short* qb = q_ws + base;
  const unsigned short* kb = k_ws + base;
  const unsigned short* vb = v_ws + base;
  // stage V: read [s][d] coalesced; scatter to sigma-slot layout Vt[d][col]
#pragma unroll
  for (int it = 0; it < 8; ++it) {
    int idx = it * 256 + tid;
    int s = idx >> 2, kk = idx & 3, d0 = kk * 8;
    bf16x8 vv = *(const bf16x8*)(vb + s * 32 + d0);
    int col = (s & ~31) + ((s >> 2) & 3) * 8 + ((s >> 4) & 1) * 4 + (s & 3);
#pragma unroll
    for (int j = 0; j < 8; ++j) Vt[(d0 + j) * VT_LD + col] = (unsigned short)vv[j];
  }
  __syncthreads();

  int r16 = lane & 15, g = lane >> 4;
  const unsigned* bh_ = biasf + (size_t)h * 131072 + lane * 2;
  unsigned short* ob = attn_out + base;            // [b][h][s][32]
  const f32x4 zero = {0.f, 0.f, 0.f, 0.f};

  for (int qt = 0; qt < 2; ++qt) {
    int qbase = quarter * 128 + (wave * 2 + qt) * 16;
    const unsigned* bq = bh_ + (size_t)(qbase >> 4) * 4096;
    // qf = B-operand: Q[q = lane&15][d = g*8+j]
    bf16x8 qf = *(const bf16x8*)(qb + (qbase + r16) * 32 + g * 8);
    f32x4 o0 = zero, o1 = zero;
    float smA = 0.f, smB = 0.f, smC = 0.f, smD = 0.f;
#pragma unroll
    for (int c = 0; c < 16; ++c) {
      // kf = A-operand: K[k = t*16 + lane&15][d = g*8+j]
      bf16x8 kf0 = *(const bf16x8*)(kb + ((c * 2) * 16 + r16) * 32 + g * 8);
      bf16x8 kf1 = *(const bf16x8*)(kb + ((c * 2 + 1) * 16 + r16) * 32 + g * 8);
      uint2 u0 = *(const uint2*)(bq + (c * 2) * 128);
      uint2 u1 = *(const uint2*)(bq + (c * 2 + 1) * 128);
      // D[k][q]: reg r -> k = t*16 + 4g + r, col = q
      f32x4 s0 = __builtin_amdgcn_mfma_f32_16x16x32_bf16(kf0, qf, zero, 0, 0, 0);
      f32x4 s1 = __builtin_amdgcn_mfma_f32_16x16x32_bf16(kf1, qf, zero, 0, 0, 0);
      s0[0] += bflo(u0.x); s0[1] += bfhi(u0.x);
      s0[2] += bflo(u0.y); s0[3] += bfhi(u0.y);
      s1[0] += bflo(u1.x); s1[1] += bfhi(u1.x);
      s1[2] += bflo(u1.y); s1[3] += bfhi(u1.y);
#pragma unroll
      for (int r = 0; r < 4; ++r) {
        s0[r] = exp2f(s0[r]);
        s1[r] = exp2f(s1[r]);
      }
      smA += s0[0] + s1[0];
      smB += s0[1] + s1[1];
      smC += s0[2] + s1[2];
      smD += s0[3] + s1[3];
      // P as A-operand in regs: words (s0 pair, s0 pair, s1 pair, s1 pair)
      union { unsigned u[4]; bf16x8 v; } pa;
      pa.u[0] = cvt_pk_bf16(s0[0], s0[1]);
      pa.u[1] = cvt_pk_bf16(s0[2], s0[3]);
      pa.u[2] = cvt_pk_bf16(s1[0], s1[1]);
      pa.u[3] = cvt_pk_bf16(s1[2], s1[3]);
      bf16x8 vf0 = *(const bf16x8*)(Vt + r16 * VT_LD + c * 32 + g * 8);
      bf16x8 vf1 = *(const bf16x8*)(Vt + (r16 + 16) * VT_LD + c * 32 + g * 8);
      o0 = __builtin_amdgcn_mfma_f32_16x16x32_bf16(pa.v, vf0, o0, 0, 0, 0);
      o1 = __builtin_amdgcn_mfma_f32_16x16x32_bf16(pa.v, vf1, o1, 0, 0, 0);
    }
    // row sum for q = lane&15 (lanes l, l^16, l^32, l^48 hold partials)
    float S = smA + smB + smC + smD;
    S += __shfl_xor(S, 16, 64);
    S += __shfl_xor(S, 32, 64);
    float invS = 1.0f / S;
    // output rows are q = 4g + r: pull inv from lane (4g+r)
#pragma unroll
    for (int r = 0; r < 4; ++r) {
      float ir = __int_as_float(
          __builtin_amdgcn_ds_bpermute((4 * g + r) * 4, __float_as_int(invS)));
      int s = qbase + g * 4 + r;
      unsigned pk = cvt_pk_bf16(o0[r] * ir, o1[r] * ir);
      *(unsigned*)(ob + (size_t)s * 32 + r16 * 2) = pk;   // 64B runs
    }
  }
}

// ---------------------------------------------------------------------------
extern "C" void kernel_launch(void* const* d_in, const int* in_sizes, int n_in,
                              void* d_out, int out_size, void* d_ws, size_t ws_size,
                              hipStream_t stream) {
  (void)in_sizes; (void)n_in; (void)out_size; (void)ws_size;
  const float* m        = (const float*)d_in[0];
  const float* z        = (const float*)d_in[1];
  const float* z_mask   = (const float*)d_in[2];
  const float* w_norm_m = (const float*)d_in[3];
  const float* w_norm_z = (const float*)d_in[4];
  const float* Wq = (const float*)d_in[5];
  const float* Wk = (const float*)d_in[6];
  const float* Wv = (const float*)d_in[7];
  const float* Wz = (const float*)d_in[8];
  const float* Wg = (const float*)d_in[9];
  const float* bg = (const float*)d_in[10];
  const float* Wo = (const float*)d_in[11];
  const float* bo = (const float*)d_in[12];
  float* out = (float*)d_out;

  char* ws = (char*)d_ws;
  size_t off = 0;
  unsigned short* m_norm  = (unsigned short*)(ws + off); off += (size_t)32768 * 256 * 2;
  unsigned short* Wt_qkvg = (unsigned short*)(ws + off); off += (size_t)1024 * 256 * 2;
  unsigned short* Wt_o    = (unsigned short*)(ws + off); off += (size_t)256 * 256 * 2;
  unsigned short* q_ws    = (unsigned short*)(ws + off); off += (size_t)64 * 8 * 512 * 32 * 2;
  unsigned short* k_ws    = (unsigned short*)(ws + off); off += (size_t)64 * 8 * 512 * 32 * 2;
  unsigned short* v_ws    = (unsigned short*)(ws + off); off += (size_t)64 * 8 * 512 * 32 * 2;
  float* g_ws             = (float*)(ws + off);          off += (size_t)32768 * 256 * 4;
  unsigned* biasf         = (unsigned*)(ws + off);       off += (size_t)8 * 32 * 32 * 128 * 4;
  unsigned short* attn_out = m_norm;  // m_norm dead after k_gemm_qkvg

  hipLaunchKernelGGL(k_cast_weights, dim3(1280), dim3(256), 0, stream,
                     Wq, Wk, Wv, Wg, Wo, Wt_qkvg, Wt_o);
  hipLaunchKernelGGL(k_rmsnorm_m, dim3(8192), dim3(256), 0, stream, m, w_norm_m, m_norm);
  hipLaunchKernelGGL(k_pair_bias, dim3(4096), dim3(256), 0, stream,
                     z, z_mask, w_norm_z, Wz, biasf);
  hipLaunchKernelGGL(k_gemm_qkvg, dim3(256, 8), dim3(256), 0, stream,
                     m_norm, Wt_qkvg, bg, q_ws, k_ws, v_ws, g_ws);
  hipLaunchKernelGGL(k_attn, dim3(2048), dim3(256), 0, stream,
                     q_ws, k_ws, v_ws, biasf, attn_out);
  hipLaunchKernelGGL(k_gemm_out, dim3(256, 2), dim3(256), 0, stream,
                     attn_out, Wt_o, bo, g_ws, out);
}

// Round 8
// 182.781 us; speedup vs baseline: 2.3444x; 1.0509x over previous
//
#include <hip/hip_runtime.h>

typedef short bf16x8 __attribute__((ext_vector_type(8)));
typedef float f32x4 __attribute__((ext_vector_type(4)));

#define DI __device__ __forceinline__

#define LOG2E 1.44269504088896f
#define QSCALE (0.17677669529663687f * 1.44269504088896f)

static DI unsigned short f2bf(float f) {
  union { float f; unsigned u; } v; v.f = f;
  unsigned r = v.u + 0x7FFFu + ((v.u >> 16) & 1u);  // RNE
  return (unsigned short)(r >> 16);
}

static DI unsigned cvt_pk_bf16(float lo, float hi) {
  unsigned r;
  asm("v_cvt_pk_bf16_f32 %0, %1, %2" : "=v"(r) : "v"(lo), "v"(hi));
  return r;
}

static DI float bflo(unsigned u) { return __uint_as_float(u << 16); }
static DI float bfhi(unsigned u) { return __uint_as_float(u & 0xffff0000u); }

// Async global->LDS, 16B per lane. LDS dest is wave-uniform base + lane*16.
static DI void gld16(const void* g, void* l) {
  __builtin_amdgcn_global_load_lds((__attribute__((address_space(1))) void*)g,
                                   (__attribute__((address_space(3))) void*)l,
                                   16, 0, 0);
}

// ---------------------------------------------------------------------------
// Weight prep. Wt_qkvg: [N=1024][K=256] bf16 n-major. Wt_o: rows k-PERMUTED
// with pi(h*32+d) = h*32 + (d&15)*2 + (d>>4) to match attn_out's packed
// per-head column layout (k-permutation on both GEMM operands = no-op).
// ---------------------------------------------------------------------------
__global__ __launch_bounds__(256) void k_cast_weights(
    const float* __restrict__ Wq, const float* __restrict__ Wk,
    const float* __restrict__ Wv, const float* __restrict__ Wg,
    const float* __restrict__ Wo,
    unsigned short* __restrict__ Wt_qkvg, unsigned short* __restrict__ Wt_o) {
  int t = blockIdx.x * 256 + threadIdx.x;
  if (t < 262144) {
    int n = t & 1023, kk = t >> 10;
    const float* W = (n < 256) ? Wq : (n < 512) ? Wk : (n < 768) ? Wv : Wg;
    Wt_qkvg[(size_t)n * 256 + kk] = f2bf(W[kk * 256 + (n & 255)]);
  } else if (t < 262144 + 65536) {
    int u = t - 262144;
    int n = u & 255, kk = u >> 8;
    int h = kk >> 5, e = kk & 31;
    int d = (e >> 1) + ((e & 1) << 4);  // pi^-1
    Wt_o[n * 256 + kk] = f2bf(Wo[(h * 32 + d) * 256 + n]);
  }
}

// ---------------------------------------------------------------------------
// rmsnorm(m) -> bf16. One wave per 256-elem row, float4 per lane.
// ---------------------------------------------------------------------------
__global__ __launch_bounds__(256) void k_rmsnorm_m(
    const float* __restrict__ m, const float* __restrict__ w,
    unsigned short* __restrict__ m_norm) {
  int wave = threadIdx.x >> 6, lane = threadIdx.x & 63;
  int row = blockIdx.x * 4 + wave;
  const float4 x = *(const float4*)(m + (size_t)row * 256 + lane * 4);
  float ss = x.x * x.x + x.y * x.y + x.z * x.z + x.w * x.w;
#pragma unroll
  for (int mk = 1; mk < 64; mk <<= 1) ss += __shfl_xor(ss, mk, 64);
  float rms = rsqrtf(ss * (1.0f / 256.0f) + 1e-5f);
  const float4 wv = *(const float4*)(w + lane * 4);
  ushort4 o;
  o.x = f2bf(x.x * rms * wv.x);
  o.y = f2bf(x.y * rms * wv.y);
  o.z = f2bf(x.z * rms * wv.z);
  o.w = f2bf(x.w * rms * wv.w);
  *(ushort4*)(m_norm + (size_t)row * 256 + lane * 4) = o;
}

// ---------------------------------------------------------------------------
// Pair bias -> bf16 packed SWAPPED-C-fragment layout, pre-scaled by log2(e).
// Attn computes D[k][q] = mfma(K,Q): lane l needs bias(i=q=l&15 of its tile,
// k = t*16 + 4*(l>>4) + r). Pack pairs along k (j0 even, j0+1):
//   u32 biasf[h][i16][t][l][w], l = (i&15) + 16*((j0&15)>>2), w = (j0>>1)&1
// Wave: half 0 -> j0 (even), half 1 -> j0+1, same i; pack via shfl_xor(32).
// z loads coalesced (2 adjacent rows = 1KB per wave).
// ---------------------------------------------------------------------------
__global__ __launch_bounds__(256) void k_pair_bias(
    const float* __restrict__ z, const float* __restrict__ z_mask,
    const float* __restrict__ w_norm_z, const float* __restrict__ Wz,
    unsigned* __restrict__ biasf) {
  int gw = blockIdx.x * 4 + (threadIdx.x >> 6);   // global wave 0..16383
  int lane = threadIdx.x & 63;
  int half = lane >> 5, li = lane & 31;
  f32x4 wzl[4], wzh[4];
#pragma unroll
  for (int i = 0; i < 4; ++i) {
    wzl[i] = *(const f32x4*)(Wz + (li * 4 + i) * 8);
    wzh[i] = *(const f32x4*)(Wz + (li * 4 + i) * 8 + 4);
  }
  const float4 wn = *(const float4*)(w_norm_z + li * 4);

  for (int it = 0; it < 8; ++it) {
    int p = it * 16384 + gw;              // pair index 0..131071
    int i = p >> 8, jp = p & 255;
    int j = jp * 2 + half;                // k-col
    int rr = i * 512 + j;                 // flat z row
    const float4 a = *(const float4*)(z + (size_t)rr * 128 + li * 4);
    float mb = (z_mask[rr] > 0.0f) ? 0.0f : -1e9f;

    float ss = a.x * a.x + a.y * a.y + a.z * a.z + a.w * a.w;
#pragma unroll
    for (int mk = 1; mk < 32; mk <<= 1) ss += __shfl_xor(ss, mk, 64);
    float rms = rsqrtf(ss * (1.0f / 128.0f) + 1e-5f);

    float y0 = a.x * wn.x, y1 = a.y * wn.y, y2 = a.z * wn.z, y3 = a.w * wn.w;
    f32x4 pl = y0 * wzl[0] + y1 * wzl[1] + y2 * wzl[2] + y3 * wzl[3];
    f32x4 ph = y0 * wzh[0] + y1 * wzh[1] + y2 * wzh[2] + y3 * wzh[3];

    int b0 = li & 1, b1 = (li >> 1) & 1, b2 = (li >> 2) & 1;
    float A[4] = {pl[0], pl[2], ph[0], ph[2]};
    float Bv[4] = {pl[1], pl[3], ph[1], ph[3]};
    float keep[4];
#pragma unroll
    for (int i2 = 0; i2 < 4; ++i2) {
      float send = b0 ? A[i2] : Bv[i2];
      float recv = __shfl_xor(send, 1, 64);
      keep[i2] = (b0 ? Bv[i2] : A[i2]) + recv;
    }
    float s2x = b1 ? keep[0] : keep[1];
    float s2y = b1 ? keep[2] : keep[3];
    float r2x = __shfl_xor(s2x, 2, 64);
    float r2y = __shfl_xor(s2y, 2, 64);
    float k2x = (b1 ? keep[1] : keep[0]) + r2x;
    float k2y = (b1 ? keep[3] : keep[2]) + r2y;
    float s3 = b2 ? k2x : k2y;
    float r3 = __shfl_xor(s3, 4, 64);
    float fin = (b2 ? k2y : k2x) + r3;           // head (li&7) partial (8 lanes)
    fin += __shfl_xor(fin, 8, 64);
    fin += __shfl_xor(fin, 16, 64);              // full 32-lane row sum

    float full = (fin * rms + mb) * LOG2E;
    float fo = __shfl_xor(full, 32, 64);         // partner (j0+1) value
    if (half == 0 && li < 8) {
      unsigned pk = cvt_pk_bf16(full, fo);       // (j0, j0+1)
      int j0 = jp * 2;
      int l = (i & 15) + 16 * ((j0 & 15) >> 2);
      size_t o = ((((size_t)li * 32 + (i >> 4)) * 32 + (j0 >> 4)) * 64 + l) * 2 +
                 ((jp) & 1);
      biasf[o] = pk;
    }
  }
}

// ---------------------------------------------------------------------------
// 128x128 MFMA GEMM mainloop, R8: global_load_lds width-16 staging into
// LINEAR LDS [128][32] with SOURCE-side XOR swizzle (chunk (row,q) holds
// global chunk (row, q ^ ((row>>1)&3))); reads apply the same XOR ->
// conflict-free ds_read_b128 (uniform 8 dwords/bank = b128 minimum).
// Per wave per K-step: 4x global_load_lds_dwordx4 (A x2, B x2) + 16 MFMA.
// Astep: element advance per K-step (32 for row-major A; 16384 for the
// per-head gathered attn layout in k_gemm_out).
// ---------------------------------------------------------------------------
DI void gemm_mainloop_g(const unsigned short* a0, const unsigned short* a1,
                        const unsigned short* b0, const unsigned short* b1,
                        size_t Astep, unsigned short* At, unsigned short* Bts,
                        f32x4 acc[4][4]) {
  int tid = threadIdx.x, lane = tid & 63, w = tid >> 6;
  int wm = w >> 1, wn = w & 1;
  int r16 = lane & 15, g = lane >> 4;
  int gx = (g ^ ((r16 >> 1) & 3)) * 8;
  unsigned short* lA0 = At + w * 1024;
  unsigned short* lA1 = At + w * 1024 + 512;
  unsigned short* lB0 = Bts + w * 1024;
  unsigned short* lB1 = Bts + w * 1024 + 512;
  for (int ks = 0; ks < 8; ++ks) {
    gld16(a0 + ks * Astep, lA0);
    gld16(a1 + ks * Astep, lA1);
    gld16(b0 + ks * 32, lB0);
    gld16(b1 + ks * 32, lB1);
    __syncthreads();
    bf16x8 af[4], bfr[4];
#pragma unroll
    for (int i = 0; i < 4; ++i)
      af[i] = *(const bf16x8*)(At + (wm * 64 + i * 16 + r16) * 32 + gx);
#pragma unroll
    for (int j = 0; j < 4; ++j)
      bfr[j] = *(const bf16x8*)(Bts + (wn * 64 + j * 16 + r16) * 32 + gx);
#pragma unroll
    for (int i = 0; i < 4; ++i)
#pragma unroll
      for (int j = 0; j < 4; ++j)
        acc[i][j] = __builtin_amdgcn_mfma_f32_16x16x32_bf16(af[i], bfr[j],
                                                            acc[i][j], 0, 0, 0);
    __syncthreads();
  }
}

// GEMM 1: m_norm @ [Wq|Wk|Wv|Wg]. q pre-scaled by 1/sqrt(D)*log2(e).
__global__ __launch_bounds__(256) void k_gemm_qkvg(
    const unsigned short* __restrict__ m_norm, const unsigned short* __restrict__ Wt,
    const float* __restrict__ bg,
    unsigned short* __restrict__ q_ws, unsigned short* __restrict__ k_ws,
    unsigned short* __restrict__ v_ws, float* __restrict__ g_ws) {
  __shared__ unsigned short At[4096];
  __shared__ unsigned short Bts[4096];
  int mb = blockIdx.x * 128, nb = blockIdx.y * 128;
  int tid = threadIdx.x, lane = tid & 63, w = tid >> 6;
  int c0 = w * 128 + lane, c1 = c0 + 64;
  int row0 = c0 >> 2, q0 = (c0 & 3) ^ ((row0 >> 1) & 3);
  int row1 = c1 >> 2, q1 = (c1 & 3) ^ ((row1 >> 1) & 3);
  f32x4 acc[4][4] = {};
  gemm_mainloop_g(m_norm + (size_t)(mb + row0) * 256 + q0 * 8,
                  m_norm + (size_t)(mb + row1) * 256 + q1 * 8,
                  Wt + (size_t)(nb + row0) * 256 + q0 * 8,
                  Wt + (size_t)(nb + row1) * 256 + q1 * 8,
                  32, At, Bts, acc);
  int wm = w >> 1, wn = w & 1;
  int r16 = lane & 15, rg = lane >> 4;
#pragma unroll
  for (int i = 0; i < 4; ++i)
#pragma unroll
    for (int j = 0; j < 4; ++j) {
      int n = nb + wn * 64 + j * 16 + r16;
#pragma unroll
      for (int r = 0; r < 4; ++r) {
        int mrow = mb + wm * 64 + i * 16 + rg * 4 + r;
        int bb = mrow >> 9, s = mrow & 511;
        float v = acc[i][j][r];
        if (n < 768) {
          int tsel = n >> 8, hh = (n >> 5) & 7, dd = n & 31;
          unsigned short* dst = (tsel == 0) ? q_ws : (tsel == 1) ? k_ws : v_ws;
          float vv = (tsel == 0) ? v * QSCALE : v;
          dst[(((size_t)bb * 8 + hh) * 512 + s) * 32 + dd] = f2bf(vv);
        } else {
          int n2 = n & 255;
          g_ws[(size_t)mrow * 256 + n2] = v + bg[n2];
        }
      }
    }
}

// GEMM 2: attn_out [b][h][s][32] (pi-packed cols) @ Wt_o (rows pi-permuted),
// epilogue (+bo)*g -> fp32 out. A gathered per-head: K-step advances h.
__global__ __launch_bounds__(256) void k_gemm_out(
    const unsigned short* __restrict__ attn, const unsigned short* __restrict__ Wt_o,
    const float* __restrict__ bo, const float* __restrict__ g_ws,
    float* __restrict__ out) {
  __shared__ unsigned short At[4096];
  __shared__ unsigned short Bts[4096];
  int mb = blockIdx.x * 128, nb = blockIdx.y * 128;
  int tid = threadIdx.x, lane = tid & 63, w = tid >> 6;
  int c0 = w * 128 + lane, c1 = c0 + 64;
  int row0 = c0 >> 2, q0 = (c0 & 3) ^ ((row0 >> 1) & 3);
  int row1 = c1 >> 2, q1 = (c1 & 3) ^ ((row1 >> 1) & 3);
  int mrow0 = mb + row0, mrow1 = mb + row1;
  f32x4 acc[4][4] = {};
  gemm_mainloop_g(
      attn + ((size_t)(mrow0 >> 9) * 8) * 16384 + (size_t)(mrow0 & 511) * 32 + q0 * 8,
      attn + ((size_t)(mrow1 >> 9) * 8) * 16384 + (size_t)(mrow1 & 511) * 32 + q1 * 8,
      Wt_o + (size_t)(nb + row0) * 256 + q0 * 8,
      Wt_o + (size_t)(nb + row1) * 256 + q1 * 8,
      16384, At, Bts, acc);
  int wm = w >> 1, wn = w & 1;
  int r16 = lane & 15, rg = lane >> 4;
#pragma unroll
  for (int i = 0; i < 4; ++i)
#pragma unroll
    for (int j = 0; j < 4; ++j) {
      int n = nb + wn * 64 + j * 16 + r16;
#pragma unroll
      for (int r = 0; r < 4; ++r) {
        int mrow = mb + wm * 64 + i * 16 + rg * 4 + r;
        out[(size_t)mrow * 256 + n] = (acc[i][j][r] + bo[n]) * g_ws[(size_t)mrow * 256 + n];
      }
    }
}

// ---------------------------------------------------------------------------
// Attention, R7 (unchanged): swapped QK^T (mfma(K,Q) -> D[k][q]) so P is a
// valid PV A-operand IN REGISTERS (4 cvt_pk, no LDS round trip). PV k-order
// sigma: group g holds k in {4g..4g+3, 16+4g..16+4g+3}; V staged at slot
// 8*((sc>>2)&3) + 4*((sc>>4)&1) + (sc&3) so vf = one ds_read_b128. VT_LD=522.
// Grid 2048 = quarter*512 + h*64 + b (quarters of (b,h) on same XCD).
// ---------------------------------------------------------------------------
#define VT_LD 522
__global__ __launch_bounds__(256, 2) void k_attn(
    const unsigned short* __restrict__ q_ws, const unsigned short* __restrict__ k_ws,
    const unsigned short* __restrict__ v_ws, const unsigned* __restrict__ biasf,
    unsigned short* __restrict__ attn_out) {
  __shared__ unsigned short Vt[32 * VT_LD];        // 33,408 B
  int tid = threadIdx.x;
  int wave = tid >> 6, lane = tid & 63;
  int bx = blockIdx.x;
  int quarter = bx >> 9, h = (bx >> 6) & 7, b = bx & 63;
  size_t base = ((size_t)b * 8 + h) * (512 * 32);
  const unsigned short* qb = q_ws + base;
  const unsigned short* kb = k_ws + base;
  const unsigned short* vb = v_ws + base;
#pragma unroll
  for (int it = 0; it < 8; ++it) {
    int idx = it * 256 + tid;
    int s = idx >> 2, kk = idx & 3, d0 = kk * 8;
    bf16x8 vv = *(const bf16x8*)(vb + s * 32 + d0);
    int col = (s & ~31) + ((s >> 2) & 3) * 8 + ((s >> 4) & 1) * 4 + (s & 3);
#pragma unroll
    for (int j = 0; j < 8; ++j) Vt[(d0 + j) * VT_LD + col] = (unsigned short)vv[j];
  }
  __syncthreads();

  int r16 = lane & 15, g = lane >> 4;
  const unsigned* bh_ = biasf + (size_t)h * 131072 + lane * 2;
  unsigned short* ob = attn_out + base;            // [b][h][s][32]
  const f32x4 zero = {0.f, 0.f, 0.f, 0.f};

  for (int qt = 0; qt < 2; ++qt) {
    int qbase = quarter * 128 + (wave * 2 + qt) * 16;
    const unsigned* bq = bh_ + (size_t)(qbase >> 4) * 4096;
    bf16x8 qf = *(const bf16x8*)(qb + (qbase + r16) * 32 + g * 8);
    f32x4 o0 = zero, o1 = zero;
    float smA = 0.f, smB = 0.f, smC = 0.f, smD = 0.f;
#pragma unroll
    for (int c = 0; c < 16; ++c) {
      bf16x8 kf0 = *(const bf16x8*)(kb + ((c * 2) * 16 + r16) * 32 + g * 8);
      bf16x8 kf1 = *(const bf16x8*)(kb + ((c * 2 + 1) * 16 + r16) * 32 + g * 8);
      uint2 u0 = *(const uint2*)(bq + (c * 2) * 128);
      uint2 u1 = *(const uint2*)(bq + (c * 2 + 1) * 128);
      f32x4 s0 = __builtin_amdgcn_mfma_f32_16x16x32_bf16(kf0, qf, zero, 0, 0, 0);
      f32x4 s1 = __builtin_amdgcn_mfma_f32_16x16x32_bf16(kf1, qf, zero, 0, 0, 0);
      s0[0] += bflo(u0.x); s0[1] += bfhi(u0.x);
      s0[2] += bflo(u0.y); s0[3] += bfhi(u0.y);
      s1[0] += bflo(u1.x); s1[1] += bfhi(u1.x);
      s1[2] += bflo(u1.y); s1[3] += bfhi(u1.y);
#pragma unroll
      for (int r = 0; r < 4; ++r) {
        s0[r] = exp2f(s0[r]);
        s1[r] = exp2f(s1[r]);
      }
      smA += s0[0] + s1[0];
      smB += s0[1] + s1[1];
      smC += s0[2] + s1[2];
      smD += s0[3] + s1[3];
      union { unsigned u[4]; bf16x8 v; } pa;
      pa.u[0] = cvt_pk_bf16(s0[0], s0[1]);
      pa.u[1] = cvt_pk_bf16(s0[2], s0[3]);
      pa.u[2] = cvt_pk_bf16(s1[0], s1[1]);
      pa.u[3] = cvt_pk_bf16(s1[2], s1[3]);
      bf16x8 vf0 = *(const bf16x8*)(Vt + r16 * VT_LD + c * 32 + g * 8);
      bf16x8 vf1 = *(const bf16x8*)(Vt + (r16 + 16) * VT_LD + c * 32 + g * 8);
      o0 = __builtin_amdgcn_mfma_f32_16x16x32_bf16(pa.v, vf0, o0, 0, 0, 0);
      o1 = __builtin_amdgcn_mfma_f32_16x16x32_bf16(pa.v, vf1, o1, 0, 0, 0);
    }
    float S = smA + smB + smC + smD;
    S += __shfl_xor(S, 16, 64);
    S += __shfl_xor(S, 32, 64);
    float invS = 1.0f / S;
#pragma unroll
    for (int r = 0; r < 4; ++r) {
      float ir = __int_as_float(
          __builtin_amdgcn_ds_bpermute((4 * g + r) * 4, __float_as_int(invS)));
      int s = qbase + g * 4 + r;
      unsigned pk = cvt_pk_bf16(o0[r] * ir, o1[r] * ir);
      *(unsigned*)(ob + (size_t)s * 32 + r16 * 2) = pk;   // 64B runs
    }
  }
}

// ---------------------------------------------------------------------------
extern "C" void kernel_launch(void* const* d_in, const int* in_sizes, int n_in,
                              void* d_out, int out_size, void* d_ws, size_t ws_size,
                              hipStream_t stream) {
  (void)in_sizes; (void)n_in; (void)out_size; (void)ws_size;
  const float* m        = (const float*)d_in[0];
  const float* z        = (const float*)d_in[1];
  const float* z_mask   = (const float*)d_in[2];
  const float* w_norm_m = (const float*)d_in[3];
  const float* w_norm_z = (const float*)d_in[4];
  const float* Wq = (const float*)d_in[5];
  const float* Wk = (const float*)d_in[6];
  const float* Wv = (const float*)d_in[7];
  const float* Wz = (const float*)d_in[8];
  const float* Wg = (const float*)d_in[9];
  const float* bg = (const float*)d_in[10];
  const float* Wo = (const float*)d_in[11];
  const float* bo = (const float*)d_in[12];
  float* out = (float*)d_out;

  char* ws = (char*)d_ws;
  size_t off = 0;
  unsigned short* m_norm  = (unsigned short*)(ws + off); off += (size_t)32768 * 256 * 2;
  unsigned short* Wt_qkvg = (unsigned short*)(ws + off); off += (size_t)1024 * 256 * 2;
  unsigned short* Wt_o    = (unsigned short*)(ws + off); off += (size_t)256 * 256 * 2;
  unsigned short* q_ws    = (unsigned short*)(ws + off); off += (size_t)64 * 8 * 512 * 32 * 2;
  unsigned short* k_ws    = (unsigned short*)(ws + off); off += (size_t)64 * 8 * 512 * 32 * 2;
  unsigned short* v_ws    = (unsigned short*)(ws + off); off += (size_t)64 * 8 * 512 * 32 * 2;
  float* g_ws             = (float*)(ws + off);          off += (size_t)32768 * 256 * 4;
  unsigned* biasf         = (unsigned*)(ws + off);       off += (size_t)8 * 32 * 32 * 128 * 4;
  unsigned short* attn_out = m_norm;  // m_norm dead after k_gemm_qkvg

  hipLaunchKernelGGL(k_cast_weights, dim3(1280), dim3(256), 0, stream,
                     Wq, Wk, Wv, Wg, Wo, Wt_qkvg, Wt_o);
  hipLaunchKernelGGL(k_rmsnorm_m, dim3(8192), dim3(256), 0, stream, m, w_norm_m, m_norm);
  hipLaunchKernelGGL(k_pair_bias, dim3(4096), dim3(256), 0, stream,
                     z, z_mask, w_norm_z, Wz, biasf);
  hipLaunchKernelGGL(k_gemm_qkvg, dim3(256, 8), dim3(256), 0, stream,
                     m_norm, Wt_qkvg, bg, q_ws, k_ws, v_ws, g_ws);
  hipLaunchKernelGGL(k_attn, dim3(2048), dim3(256), 0, stream,
                     q_ws, k_ws, v_ws, biasf, attn_out);
  hipLaunchKernelGGL(k_gemm_out, dim3(256, 2), dim3(256), 0, stream,
                     attn_out, Wt_o, bo, g_ws, out);
}

// Round 11
// 179.359 us; speedup vs baseline: 2.3891x; 1.0191x over previous
//
#include <hip/hip_runtime.h>

typedef short bf16x8 __attribute__((ext_vector_type(8)));
typedef float f32x4 __attribute__((ext_vector_type(4)));

#define DI __device__ __forceinline__

#define LOG2E 1.44269504088896f
#define QSCALE (0.17677669529663687f * 1.44269504088896f)

static DI unsigned short f2bf(float f) {
  union { float f; unsigned u; } v; v.f = f;
  unsigned r = v.u + 0x7FFFu + ((v.u >> 16) & 1u);  // RNE
  return (unsigned short)(r >> 16);
}

static DI unsigned cvt_pk_bf16(float lo, float hi) {
  unsigned r;
  asm("v_cvt_pk_bf16_f32 %0, %1, %2" : "=v"(r) : "v"(lo), "v"(hi));
  return r;
}

static DI float bflo(unsigned u) { return __uint_as_float(u << 16); }
static DI float bfhi(unsigned u) { return __uint_as_float(u & 0xffff0000u); }

// Async global->LDS, 16B per lane. LDS dest is wave-uniform base + lane*16.
static DI void gld16(const void* g, void* l) {
  __builtin_amdgcn_global_load_lds((__attribute__((address_space(1))) void*)g,
                                   (__attribute__((address_space(3))) void*)l,
                                   16, 0, 0);
}

// ---------------------------------------------------------------------------
// Weight prep. Wt_qkvg: [N=1024][K=256] bf16 n-major. Wt_o: rows k-PERMUTED
// with pi(h*32+d) = h*32 + (d&15)*2 + (d>>4) to match attn_out's packed
// per-head column layout (k-permutation on both GEMM operands = no-op).
// ---------------------------------------------------------------------------
__global__ __launch_bounds__(256) void k_cast_weights(
    const float* __restrict__ Wq, const float* __restrict__ Wk,
    const float* __restrict__ Wv, const float* __restrict__ Wg,
    const float* __restrict__ Wo,
    unsigned short* __restrict__ Wt_qkvg, unsigned short* __restrict__ Wt_o) {
  int t = blockIdx.x * 256 + threadIdx.x;
  if (t < 262144) {
    int n = t & 1023, kk = t >> 10;
    const float* W = (n < 256) ? Wq : (n < 512) ? Wk : (n < 768) ? Wv : Wg;
    Wt_qkvg[(size_t)n * 256 + kk] = f2bf(W[kk * 256 + (n & 255)]);
  } else if (t < 262144 + 65536) {
    int u = t - 262144;
    int n = u & 255, kk = u >> 8;
    int h = kk >> 5, e = kk & 31;
    int d = (e >> 1) + ((e & 1) << 4);  // pi^-1
    Wt_o[n * 256 + kk] = f2bf(Wo[(h * 32 + d) * 256 + n]);
  }
}

// ---------------------------------------------------------------------------
// rmsnorm(m) -> bf16. One wave per 256-elem row, float4 per lane.
// ---------------------------------------------------------------------------
__global__ __launch_bounds__(256) void k_rmsnorm_m(
    const float* __restrict__ m, const float* __restrict__ w,
    unsigned short* __restrict__ m_norm) {
  int wave = threadIdx.x >> 6, lane = threadIdx.x & 63;
  int row = blockIdx.x * 4 + wave;
  const float4 x = *(const float4*)(m + (size_t)row * 256 + lane * 4);
  float ss = x.x * x.x + x.y * x.y + x.z * x.z + x.w * x.w;
#pragma unroll
  for (int mk = 1; mk < 64; mk <<= 1) ss += __shfl_xor(ss, mk, 64);
  float rms = rsqrtf(ss * (1.0f / 256.0f) + 1e-5f);
  const float4 wv = *(const float4*)(w + lane * 4);
  ushort4 o;
  o.x = f2bf(x.x * rms * wv.x);
  o.y = f2bf(x.y * rms * wv.y);
  o.z = f2bf(x.z * rms * wv.z);
  o.w = f2bf(x.w * rms * wv.w);
  *(ushort4*)(m_norm + (size_t)row * 256 + lane * 4) = o;
}

// ---------------------------------------------------------------------------
// Pair bias -> bf16 packed SWAPPED-C-fragment layout, pre-scaled by log2(e).
// Attn computes D[k][q] = mfma(K,Q): lane l needs bias(i=q=l&15 of its tile,
// k = t*16 + 4*(l>>4) + r). Pack pairs along k (j0 even, j0+1):
//   u32 biasf[h][i16][t][l][w], l = (i&15) + 16*((j0&15)>>2), w = (j0>>1)&1
// Wave: half 0 -> j0 (even), half 1 -> j0+1, same i; pack via shfl_xor(32).
// z loads coalesced (2 adjacent rows = 1KB per wave).
// ---------------------------------------------------------------------------
__global__ __launch_bounds__(256) void k_pair_bias(
    const float* __restrict__ z, const float* __restrict__ z_mask,
    const float* __restrict__ w_norm_z, const float* __restrict__ Wz,
    unsigned* __restrict__ biasf) {
  int gw = blockIdx.x * 4 + (threadIdx.x >> 6);   // global wave 0..16383
  int lane = threadIdx.x & 63;
  int half = lane >> 5, li = lane & 31;
  f32x4 wzl[4], wzh[4];
#pragma unroll
  for (int i = 0; i < 4; ++i) {
    wzl[i] = *(const f32x4*)(Wz + (li * 4 + i) * 8);
    wzh[i] = *(const f32x4*)(Wz + (li * 4 + i) * 8 + 4);
  }
  const float4 wn = *(const float4*)(w_norm_z + li * 4);

  for (int it = 0; it < 8; ++it) {
    int p = it * 16384 + gw;              // pair index 0..131071
    int i = p >> 8, jp = p & 255;
    int j = jp * 2 + half;                // k-col
    int rr = i * 512 + j;                 // flat z row
    const float4 a = *(const float4*)(z + (size_t)rr * 128 + li * 4);
    float mb = (z_mask[rr] > 0.0f) ? 0.0f : -1e9f;

    float ss = a.x * a.x + a.y * a.y + a.z * a.z + a.w * a.w;
#pragma unroll
    for (int mk = 1; mk < 32; mk <<= 1) ss += __shfl_xor(ss, mk, 64);
    float rms = rsqrtf(ss * (1.0f / 128.0f) + 1e-5f);

    float y0 = a.x * wn.x, y1 = a.y * wn.y, y2 = a.z * wn.z, y3 = a.w * wn.w;
    f32x4 pl = y0 * wzl[0] + y1 * wzl[1] + y2 * wzl[2] + y3 * wzl[3];
    f32x4 ph = y0 * wzh[0] + y1 * wzh[1] + y2 * wzh[2] + y3 * wzh[3];

    int b0 = li & 1, b1 = (li >> 1) & 1, b2 = (li >> 2) & 1;
    float A[4] = {pl[0], pl[2], ph[0], ph[2]};
    float Bv[4] = {pl[1], pl[3], ph[1], ph[3]};
    float keep[4];
#pragma unroll
    for (int i2 = 0; i2 < 4; ++i2) {
      float send = b0 ? A[i2] : Bv[i2];
      float recv = __shfl_xor(send, 1, 64);
      keep[i2] = (b0 ? Bv[i2] : A[i2]) + recv;
    }
    float s2x = b1 ? keep[0] : keep[1];
    float s2y = b1 ? keep[2] : keep[3];
    float r2x = __shfl_xor(s2x, 2, 64);
    float r2y = __shfl_xor(s2y, 2, 64);
    float k2x = (b1 ? keep[1] : keep[0]) + r2x;
    float k2y = (b1 ? keep[3] : keep[2]) + r2y;
    float s3 = b2 ? k2x : k2y;
    float r3 = __shfl_xor(s3, 4, 64);
    float fin = (b2 ? k2y : k2x) + r3;           // head (li&7) partial (8 lanes)
    fin += __shfl_xor(fin, 8, 64);
    fin += __shfl_xor(fin, 16, 64);              // full 32-lane row sum

    float full = (fin * rms + mb) * LOG2E;
    float fo = __shfl_xor(full, 32, 64);         // partner (j0+1) value
    if (half == 0 && li < 8) {
      unsigned pk = cvt_pk_bf16(full, fo);       // (j0, j0+1)
      int j0 = jp * 2;
      int l = (i & 15) + 16 * ((j0 & 15) >> 2);
      size_t o = ((((size_t)li * 32 + (i >> 4)) * 32 + (j0 >> 4)) * 64 + l) * 2 +
                 ((jp) & 1);
      biasf[o] = pk;
    }
  }
}

// ---------------------------------------------------------------------------
// 128x128 MFMA GEMM mainloop (R8-proven): global_load_lds width-16 staging
// into LINEAR LDS [128][32] with SOURCE-side XOR swizzle (chunk (row,q) holds
// global chunk (row, q ^ ((row>>1)&3))); reads apply the same XOR.
// ---------------------------------------------------------------------------
DI void gemm_mainloop_g(const unsigned short* a0, const unsigned short* a1,
                        const unsigned short* b0, const unsigned short* b1,
                        size_t Astep, unsigned short* At, unsigned short* Bts,
                        f32x4 acc[4][4]) {
  int tid = threadIdx.x, lane = tid & 63, w = tid >> 6;
  int wm = w >> 1, wn = w & 1;
  int r16 = lane & 15, g = lane >> 4;
  int gx = (g ^ ((r16 >> 1) & 3)) * 8;
  unsigned short* lA0 = At + w * 1024;
  unsigned short* lA1 = At + w * 1024 + 512;
  unsigned short* lB0 = Bts + w * 1024;
  unsigned short* lB1 = Bts + w * 1024 + 512;
  for (int ks = 0; ks < 8; ++ks) {
    gld16(a0 + ks * Astep, lA0);
    gld16(a1 + ks * Astep, lA1);
    gld16(b0 + ks * 32, lB0);
    gld16(b1 + ks * 32, lB1);
    __syncthreads();
    bf16x8 af[4], bfr[4];
#pragma unroll
    for (int i = 0; i < 4; ++i)
      af[i] = *(const bf16x8*)(At + (wm * 64 + i * 16 + r16) * 32 + gx);
#pragma unroll
    for (int j = 0; j < 4; ++j)
      bfr[j] = *(const bf16x8*)(Bts + (wn * 64 + j * 16 + r16) * 32 + gx);
#pragma unroll
    for (int i = 0; i < 4; ++i)
#pragma unroll
      for (int j = 0; j < 4; ++j)
        acc[i][j] = __builtin_amdgcn_mfma_f32_16x16x32_bf16(af[i], bfr[j],
                                                            acc[i][j], 0, 0, 0);
    __syncthreads();
  }
}

// GEMM 1: m_norm @ [Wq|Wk|Wv|Wg]. q pre-scaled by 1/sqrt(D)*log2(e).
__global__ __launch_bounds__(256) void k_gemm_qkvg(
    const unsigned short* __restrict__ m_norm, const unsigned short* __restrict__ Wt,
    const float* __restrict__ bg,
    unsigned short* __restrict__ q_ws, unsigned short* __restrict__ k_ws,
    unsigned short* __restrict__ v_ws, float* __restrict__ g_ws) {
  __shared__ unsigned short At[4096];
  __shared__ unsigned short Bts[4096];
  int mb = blockIdx.x * 128, nb = blockIdx.y * 128;
  int tid = threadIdx.x, lane = tid & 63, w = tid >> 6;
  int c0 = w * 128 + lane, c1 = c0 + 64;
  int row0 = c0 >> 2, q0 = (c0 & 3) ^ ((row0 >> 1) & 3);
  int row1 = c1 >> 2, q1 = (c1 & 3) ^ ((row1 >> 1) & 3);
  f32x4 acc[4][4] = {};
  gemm_mainloop_g(m_norm + (size_t)(mb + row0) * 256 + q0 * 8,
                  m_norm + (size_t)(mb + row1) * 256 + q1 * 8,
                  Wt + (size_t)(nb + row0) * 256 + q0 * 8,
                  Wt + (size_t)(nb + row1) * 256 + q1 * 8,
                  32, At, Bts, acc);
  int wm = w >> 1, wn = w & 1;
  int r16 = lane & 15, rg = lane >> 4;
#pragma unroll
  for (int i = 0; i < 4; ++i)
#pragma unroll
    for (int j = 0; j < 4; ++j) {
      int n = nb + wn * 64 + j * 16 + r16;
#pragma unroll
      for (int r = 0; r < 4; ++r) {
        int mrow = mb + wm * 64 + i * 16 + rg * 4 + r;
        int bb = mrow >> 9, s = mrow & 511;
        float v = acc[i][j][r];
        if (n < 768) {
          int tsel = n >> 8, hh = (n >> 5) & 7, dd = n & 31;
          unsigned short* dst = (tsel == 0) ? q_ws : (tsel == 1) ? k_ws : v_ws;
          float vv = (tsel == 0) ? v * QSCALE : v;
          dst[(((size_t)bb * 8 + hh) * 512 + s) * 32 + dd] = f2bf(vv);
        } else {
          int n2 = n & 255;
          g_ws[(size_t)mrow * 256 + n2] = v + bg[n2];
        }
      }
    }
}

// GEMM 2: attn_out [b][h][s][32] (pi-packed cols) @ Wt_o (rows pi-permuted),
// epilogue (+bo)*g -> fp32 out. A gathered per-head: K-step advances h.
__global__ __launch_bounds__(256) void k_gemm_out(
    const unsigned short* __restrict__ attn, const unsigned short* __restrict__ Wt_o,
    const float* __restrict__ bo, const float* __restrict__ g_ws,
    float* __restrict__ out) {
  __shared__ unsigned short At[4096];
  __shared__ unsigned short Bts[4096];
  int mb = blockIdx.x * 128, nb = blockIdx.y * 128;
  int tid = threadIdx.x, lane = tid & 63, w = tid >> 6;
  int c0 = w * 128 + lane, c1 = c0 + 64;
  int row0 = c0 >> 2, q0 = (c0 & 3) ^ ((row0 >> 1) & 3);
  int row1 = c1 >> 2, q1 = (c1 & 3) ^ ((row1 >> 1) & 3);
  int mrow0 = mb + row0, mrow1 = mb + row1;
  f32x4 acc[4][4] = {};
  gemm_mainloop_g(
      attn + ((size_t)(mrow0 >> 9) * 8) * 16384 + (size_t)(mrow0 & 511) * 32 + q0 * 8,
      attn + ((size_t)(mrow1 >> 9) * 8) * 16384 + (size_t)(mrow1 & 511) * 32 + q1 * 8,
      Wt_o + (size_t)(nb + row0) * 256 + q0 * 8,
      Wt_o + (size_t)(nb + row1) * 256 + q1 * 8,
      16384, At, Bts, acc);
  int wm = w >> 1, wn = w & 1;
  int r16 = lane & 15, rg = lane >> 4;
#pragma unroll
  for (int i = 0; i < 4; ++i)
#pragma unroll
    for (int j = 0; j < 4; ++j) {
      int n = nb + wn * 64 + j * 16 + r16;
#pragma unroll
      for (int r = 0; r < 4; ++r) {
        int mrow = mb + wm * 64 + i * 16 + rg * 4 + r;
        out[(size_t)mrow * 256 + n] = (acc[i][j][r] + bo[n]) * g_ws[(size_t)mrow * 256 + n];
      }
    }
}

// ---------------------------------------------------------------------------
// Attention (R8-proven structure + T5 setprio): swapped QK^T (mfma(K,Q) ->
// D[k][q], q = lane&15) so P is a valid PV A-operand IN REGISTERS (4 cvt_pk,
// no LDS round trip). PV k-order sigma: group g holds k in {4g..4g+3,
// 16+4g..16+4g+3}; V staged at slot 8*((sc>>2)&3)+4*((sc>>4)&1)+(sc&3) so
// vf = one ds_read_b128. VT_LD=522. No max pass; 1/sum at output.
// Grid 2048 = quarter*512 + h*64 + b. s_setprio(1) wraps MFMA pairs: waves
// here are barrier-free/independent (m191 regime where T5 pays).
// ---------------------------------------------------------------------------
#define VT_LD 522
__global__ __launch_bounds__(256, 2) void k_attn(
    const unsigned short* __restrict__ q_ws, const unsigned short* __restrict__ k_ws,
    const unsigned short* __restrict__ v_ws, const unsigned* __restrict__ biasf,
    unsigned short* __restrict__ attn_out) {
  __shared__ unsigned short Vt[32 * VT_LD];        // 33,408 B
  int tid = threadIdx.x;
  int wave = tid >> 6, lane = tid & 63;
  int bx = blockIdx.x;
  int quarter = bx >> 9, h = (bx >> 6) & 7, b = bx & 63;
  size_t base = ((size_t)b * 8 + h) * (512 * 32);
  const unsigned short* qb = q_ws + base;
  const unsigned short* kb = k_ws + base;
  const unsigned short* vb = v_ws + base;
#pragma unroll
  for (int it = 0; it < 8; ++it) {
    int idx = it * 256 + tid;
    int s = idx >> 2, kk = idx & 3, d0 = kk * 8;
    bf16x8 vv = *(const bf16x8*)(vb + s * 32 + d0);
    int col = (s & ~31) + ((s >> 2) & 3) * 8 + ((s >> 4) & 1) * 4 + (s & 3);
#pragma unroll
    for (int j = 0; j < 8; ++j) Vt[(d0 + j) * VT_LD + col] = (unsigned short)vv[j];
  }
  __syncthreads();

  int r16 = lane & 15, g = lane >> 4;
  const unsigned* bh_ = biasf + (size_t)h * 131072 + lane * 2;
  unsigned short* ob = attn_out + base;            // [b][h][s][32]
  const f32x4 zero = {0.f, 0.f, 0.f, 0.f};

  for (int qt = 0; qt < 2; ++qt) {
    int qbase = quarter * 128 + (wave * 2 + qt) * 16;
    const unsigned* bq = bh_ + (size_t)(qbase >> 4) * 4096;
    bf16x8 qf = *(const bf16x8*)(qb + (qbase + r16) * 32 + g * 8);
    f32x4 o0 = zero, o1 = zero;
    float smA = 0.f, smB = 0.f, smC = 0.f, smD = 0.f;
#pragma unroll
    for (int c = 0; c < 16; ++c) {
      bf16x8 kf0 = *(const bf16x8*)(kb + ((c * 2) * 16 + r16) * 32 + g * 8);
      bf16x8 kf1 = *(const bf16x8*)(kb + ((c * 2 + 1) * 16 + r16) * 32 + g * 8);
      uint2 u0 = *(const uint2*)(bq + (c * 2) * 128);
      uint2 u1 = *(const uint2*)(bq + (c * 2 + 1) * 128);
      __builtin_amdgcn_s_setprio(1);
      f32x4 s0 = __builtin_amdgcn_mfma_f32_16x16x32_bf16(kf0, qf, zero, 0, 0, 0);
      f32x4 s1 = __builtin_amdgcn_mfma_f32_16x16x32_bf16(kf1, qf, zero, 0, 0, 0);
      __builtin_amdgcn_s_setprio(0);
      s0[0] += bflo(u0.x); s0[1] += bfhi(u0.x);
      s0[2] += bflo(u0.y); s0[3] += bfhi(u0.y);
      s1[0] += bflo(u1.x); s1[1] += bfhi(u1.x);
      s1[2] += bflo(u1.y); s1[3] += bfhi(u1.y);
#pragma unroll
      for (int r = 0; r < 4; ++r) {
        s0[r] = exp2f(s0[r]);
        s1[r] = exp2f(s1[r]);
      }
      smA += s0[0] + s1[0];
      smB += s0[1] + s1[1];
      smC += s0[2] + s1[2];
      smD += s0[3] + s1[3];
      union { unsigned u[4]; bf16x8 v; } pa;
      pa.u[0] = cvt_pk_bf16(s0[0], s0[1]);
      pa.u[1] = cvt_pk_bf16(s0[2], s0[3]);
      pa.u[2] = cvt_pk_bf16(s1[0], s1[1]);
      pa.u[3] = cvt_pk_bf16(s1[2], s1[3]);
      bf16x8 vf0 = *(const bf16x8*)(Vt + r16 * VT_LD + c * 32 + g * 8);
      bf16x8 vf1 = *(const bf16x8*)(Vt + (r16 + 16) * VT_LD + c * 32 + g * 8);
      __builtin_amdgcn_s_setprio(1);
      o0 = __builtin_amdgcn_mfma_f32_16x16x32_bf16(pa.v, vf0, o0, 0, 0, 0);
      o1 = __builtin_amdgcn_mfma_f32_16x16x32_bf16(pa.v, vf1, o1, 0, 0, 0);
      __builtin_amdgcn_s_setprio(0);
    }
    float S = smA + smB + smC + smD;
    S += __shfl_xor(S, 16, 64);
    S += __shfl_xor(S, 32, 64);
    float invS = 1.0f / S;
#pragma unroll
    for (int r = 0; r < 4; ++r) {
      float ir = __int_as_float(
          __builtin_amdgcn_ds_bpermute((4 * g + r) * 4, __float_as_int(invS)));
      int s = qbase + g * 4 + r;
      unsigned pk = cvt_pk_bf16(o0[r] * ir, o1[r] * ir);
      *(unsigned*)(ob + (size_t)s * 32 + r16 * 2) = pk;   // 64B runs
    }
  }
}

// ---------------------------------------------------------------------------
extern "C" void kernel_launch(void* const* d_in, const int* in_sizes, int n_in,
                              void* d_out, int out_size, void* d_ws, size_t ws_size,
                              hipStream_t stream) {
  (void)in_sizes; (void)n_in; (void)out_size; (void)ws_size;
  const float* m        = (const float*)d_in[0];
  const float* z        = (const float*)d_in[1];
  const float* z_mask   = (const float*)d_in[2];
  const float* w_norm_m = (const float*)d_in[3];
  const float* w_norm_z = (const float*)d_in[4];
  const float* Wq = (const float*)d_in[5];
  const float* Wk = (const float*)d_in[6];
  const float* Wv = (const float*)d_in[7];
  const float* Wz = (const float*)d_in[8];
  const float* Wg = (const float*)d_in[9];
  const float* bg = (const float*)d_in[10];
  const float* Wo = (const float*)d_in[11];
  const float* bo = (const float*)d_in[12];
  float* out = (float*)d_out;

  char* ws = (char*)d_ws;
  size_t off = 0;
  unsigned short* m_norm  = (unsigned short*)(ws + off); off += (size_t)32768 * 256 * 2;
  unsigned short* Wt_qkvg = (unsigned short*)(ws + off); off += (size_t)1024 * 256 * 2;
  unsigned short* Wt_o    = (unsigned short*)(ws + off); off += (size_t)256 * 256 * 2;
  unsigned short* q_ws    = (unsigned short*)(ws + off); off += (size_t)64 * 8 * 512 * 32 * 2;
  unsigned short* k_ws    = (unsigned short*)(ws + off); off += (size_t)64 * 8 * 512 * 32 * 2;
  unsigned short* v_ws    = (unsigned short*)(ws + off); off += (size_t)64 * 8 * 512 * 32 * 2;
  float* g_ws             = (float*)(ws + off);          off += (size_t)32768 * 256 * 4;
  unsigned* biasf         = (unsigned*)(ws + off);       off += (size_t)8 * 32 * 32 * 128 * 4;
  unsigned short* attn_out = m_norm;  // m_norm dead after k_gemm_qkvg

  hipLaunchKernelGGL(k_cast_weights, dim3(1280), dim3(256), 0, stream,
                     Wq, Wk, Wv, Wg, Wo, Wt_qkvg, Wt_o);
  hipLaunchKernelGGL(k_rmsnorm_m, dim3(8192), dim3(256), 0, stream, m, w_norm_m, m_norm);
  hipLaunchKernelGGL(k_pair_bias, dim3(4096), dim3(256), 0, stream,
                     z, z_mask, w_norm_z, Wz, biasf);
  hipLaunchKernelGGL(k_gemm_qkvg, dim3(256, 8), dim3(256), 0, stream,
                     m_norm, Wt_qkvg, bg, q_ws, k_ws, v_ws, g_ws);
  hipLaunchKernelGGL(k_attn, dim3(2048), dim3(256), 0, stream,
                     q_ws, k_ws, v_ws, biasf, attn_out);
  hipLaunchKernelGGL(k_gemm_out, dim3(256, 2), dim3(256), 0, stream,
                     attn_out, Wt_o, bo, g_ws, out);
}